// Round 10
// baseline (492.009 us; speedup 1.0000x reference)
//
#include <hip/hip_runtime.h>

#define NB 2
#define SEQN 384
#define NS 1537
#define NS_PAD 1600
#define NH 8
#define H2N 16
#define NM (NB*NS)
#define DFF 1536
#define EPS1 1.1920929e-07f
#define SCAL (1.0f/48.0f)
#define SC2 (SCAL * 1.4426950408889634f)   // SCAL * log2(e), for exp2

// swizzled index into a [rows][64] 16-bit tile (16B-granule XOR swizzle)
#define SWZ(row, col) ((((row) << 6)) + ((col) ^ (((row) & 7) << 3)))

typedef __bf16 bf16x8 __attribute__((ext_vector_type(8)));
typedef _Float16 f16x8 __attribute__((ext_vector_type(8)));
typedef float f32x4 __attribute__((ext_vector_type(4)));

__device__ __forceinline__ unsigned short f2bf(float f) {
    unsigned int u = __builtin_bit_cast(unsigned int, f);
    u += 0x7FFFu + ((u >> 16) & 1u);
    return (unsigned short)(u >> 16);
}
__device__ __forceinline__ float bf2f(unsigned short h) {
    unsigned int u = ((unsigned int)h) << 16;
    return __builtin_bit_cast(float, u);
}

// ---------------- fused weight transpose (KxN f32 -> NxK bf16 hi[/lo]) ----------------
struct TD { const float* w; unsigned short* hi; unsigned short* lo; int K; int N; int perm; };
struct TD7 { TD d[7]; int tend[7]; };

__global__ __launch_bounds__(256) void transpose_all(TD7 a) {
    __shared__ float tile[32][33];
    int t = blockIdx.x;
    int i = 0;
    while (t >= a.tend[i]) i++;
    int base = (i == 0) ? 0 : a.tend[i - 1];
    int lt = t - base;
    const float* w = a.d[i].w;
    unsigned short* hi = a.d[i].hi;
    unsigned short* lo = a.d[i].lo;
    int K = a.d[i].K, N = a.d[i].N, perm = a.d[i].perm;
    int Nh = N >> 1;
    int kt = (K + 31) / 32;
    int k0 = (lt % kt) * 32, n0 = (lt / kt) * 32;
    int tx = threadIdx.x & 31, ty4 = (threadIdx.x >> 5) * 4;
    for (int q = 0; q < 4; q++) {
        int k = k0 + ty4 + q, n = n0 + tx;
        tile[ty4 + q][tx] = (k < K && n < N) ? w[(size_t)k * N + n] : 0.f;
    }
    __syncthreads();
    for (int q = 0; q < 4; q++) {
        int n = n0 + ty4 + q, k = k0 + tx;
        if (n < N && k < K) {
            float v = tile[tx][ty4 + q];
            unsigned short hb = f2bf(v);
            int n_out = perm ? ((n < Nh) ? 2 * n : 2 * (n - Nh) + 1) : n;
            size_t o = (size_t)n_out * K + k;
            hi[o] = hb;
            if (lo) lo[o] = f2bf(v - bf2f(hb));
        }
    }
}

// ---------------- rmsnorm (f32 in, bf16 hi[/lo] out) ----------------
__global__ __launch_bounds__(256) void rmsnorm_k(const float* __restrict__ in,
    const float* __restrict__ w, unsigned short* __restrict__ hi, unsigned short* __restrict__ lo,
    int in_stride, int C, float eps) {
    int row = blockIdx.x;
    const float* x = in + (size_t)row * in_stride;
    float ss = 0.f;
    for (int j = threadIdx.x; j < C; j += 256) { float v = x[j]; ss += v * v; }
    for (int o = 1; o < 64; o <<= 1) ss += __shfl_xor(ss, o);
    __shared__ float red[4];
    if ((threadIdx.x & 63) == 0) red[threadIdx.x >> 6] = ss;
    __syncthreads();
    ss = red[0] + red[1] + red[2] + red[3];
    float rs = rsqrtf(ss / (float)C + eps);
    for (int j = threadIdx.x; j < C; j += 256) {
        float y = x[j] * rs * w[j];
        unsigned short hb = f2bf(y);
        hi[(size_t)row * C + j] = hb;
        if (lo) lo[(size_t)row * C + j] = f2bf(y - bf2f(hb));
    }
}

// ---------------- dual rmsnorm: cq row -> ckvn (C=256) + qdn (C=384, cols 288..671) --
__global__ __launch_bounds__(256) void rmsnorm_dual(const float* __restrict__ cq,
    const float* __restrict__ wA, const float* __restrict__ wB,
    unsigned short* __restrict__ ah, unsigned short* __restrict__ al,
    unsigned short* __restrict__ bh_, unsigned short* __restrict__ bl_) {
    int row = blockIdx.x, tid = threadIdx.x;
    const float* xx = cq + (size_t)row * 672;
    __shared__ float red[4];
    float v = xx[tid & 255];
    float ss = v * v;
    for (int o = 1; o < 64; o <<= 1) ss += __shfl_xor(ss, o);
    if ((tid & 63) == 0) red[tid >> 6] = ss;
    __syncthreads();
    float tot = red[0] + red[1] + red[2] + red[3];
    float rs = rsqrtf(tot / 256.f + EPS1);
    float y = v * rs * wA[tid];
    unsigned short hb = f2bf(y);
    ah[(size_t)row * 256 + tid] = hb;
    al[(size_t)row * 256 + tid] = f2bf(y - bf2f(hb));
    __syncthreads();
    float v0 = xx[288 + tid];
    float v1 = (tid < 128) ? xx[288 + 256 + tid] : 0.f;
    float ss2 = v0 * v0 + v1 * v1;
    for (int o = 1; o < 64; o <<= 1) ss2 += __shfl_xor(ss2, o);
    if ((tid & 63) == 0) red[tid >> 6] = ss2;
    __syncthreads();
    tot = red[0] + red[1] + red[2] + red[3];
    rs = rsqrtf(tot / 384.f + EPS1);
    float yb = v0 * rs * wB[tid];
    hb = f2bf(yb);
    bh_[(size_t)row * 384 + tid] = hb;
    bl_[(size_t)row * 384 + tid] = f2bf(yb - bf2f(hb));
    if (tid < 128) {
        float yc = v1 * rs * wB[256 + tid];
        unsigned short hc = f2bf(yc);
        bh_[(size_t)row * 384 + 256 + tid] = hc;
        bl_[(size_t)row * 384 + 256 + tid] = f2bf(yc - bf2f(hc));
    }
}

// ------- single-bf16 GEMM, 128x64 tile, BK=64, swizzled LDS -------
__global__ __launch_bounds__(256) void gemm_single(const unsigned short* __restrict__ A,
    const unsigned short* __restrict__ Bt, float* __restrict__ C_, const float* __restrict__ res,
    int M, int N, int K) {
    __shared__ unsigned short As[128 * 64];
    __shared__ unsigned short Bs[64 * 64];
    int m0 = blockIdx.x * 128, n0 = blockIdx.y * 64;
    int tid = threadIdx.x;
    int lane = tid & 63, wid = tid >> 6;
    int wr = wid >> 1, wc = wid & 1;
    int r = lane & 15, g = lane >> 4;
    int lrow = tid >> 3, lk = (tid & 7) * 8;
    f32x4 acc[4][2] = {};
    bool aok[4]; size_t aoff[4];
    #pragma unroll
    for (int p = 0; p < 4; p++) {
        int ar = m0 + p * 32 + lrow;
        aok[p] = ar < M;
        aoff[p] = (size_t)ar * K + lk;
    }
    bool bok[2]; size_t boff[2];
    #pragma unroll
    for (int p = 0; p < 2; p++) {
        int br = n0 + p * 32 + lrow;
        bok[p] = br < N;
        boff[p] = (size_t)br * K + lk;
    }
    for (int k0 = 0; k0 < K; k0 += 64) {
        uint4 av[4], bv[2];
        #pragma unroll
        for (int p = 0; p < 4; p++) av[p] = aok[p] ? *(const uint4*)(A + aoff[p] + k0) : (uint4){0,0,0,0};
        #pragma unroll
        for (int p = 0; p < 2; p++) bv[p] = bok[p] ? *(const uint4*)(Bt + boff[p] + k0) : (uint4){0,0,0,0};
        __syncthreads();
        #pragma unroll
        for (int p = 0; p < 4; p++) *(uint4*)&As[SWZ(p * 32 + lrow, lk)] = av[p];
        #pragma unroll
        for (int p = 0; p < 2; p++) *(uint4*)&Bs[SWZ(p * 32 + lrow, lk)] = bv[p];
        __syncthreads();
        #pragma unroll
        for (int ks = 0; ks < 2; ks++) {
            bf16x8 a[4], bb[2];
            #pragma unroll
            for (int i = 0; i < 4; i++) a[i] = *(const bf16x8*)&As[SWZ(wr * 64 + i * 16 + r, ks * 32 + g * 8)];
            #pragma unroll
            for (int j = 0; j < 2; j++) bb[j] = *(const bf16x8*)&Bs[SWZ(wc * 32 + j * 16 + r, ks * 32 + g * 8)];
            #pragma unroll
            for (int i = 0; i < 4; i++)
                #pragma unroll
                for (int j = 0; j < 2; j++)
                    acc[i][j] = __builtin_amdgcn_mfma_f32_16x16x32_bf16(a[i], bb[j], acc[i][j], 0, 0, 0);
        }
    }
    #pragma unroll
    for (int i = 0; i < 4; i++)
        #pragma unroll
        for (int j = 0; j < 2; j++) {
            int col = n0 + wc * 32 + j * 16 + r;
            if (col >= N) continue;
            #pragma unroll
            for (int e = 0; e < 4; e++) {
                int row = m0 + wr * 64 + i * 16 + g * 4 + e;
                if (row >= M) continue;
                float v = acc[i][j][e];
                if (res) v += res[(size_t)row * N + col];
                C_[(size_t)row * N + col] = v;
            }
        }
}

// ------- GEMM + fused swiglu epilogue (interleaved u/g cols), BK=64 swizzled -------
__global__ __launch_bounds__(256) void gemm_swiglu(const unsigned short* __restrict__ A,
    const unsigned short* __restrict__ Bt, unsigned short* __restrict__ act,
    int M, int N, int K) {
    __shared__ unsigned short As[128 * 64];
    __shared__ unsigned short Bs[64 * 64];
    int m0 = blockIdx.x * 128, n0 = blockIdx.y * 64;
    int tid = threadIdx.x;
    int lane = tid & 63, wid = tid >> 6;
    int wr = wid >> 1, wc = wid & 1;
    int r = lane & 15, g = lane >> 4;
    int lrow = tid >> 3, lk = (tid & 7) * 8;
    f32x4 acc[4][2] = {};
    bool aok[4]; size_t aoff[4];
    #pragma unroll
    for (int p = 0; p < 4; p++) {
        int ar = m0 + p * 32 + lrow;
        aok[p] = ar < M;
        aoff[p] = (size_t)ar * K + lk;
    }
    bool bok[2]; size_t boff[2];
    #pragma unroll
    for (int p = 0; p < 2; p++) {
        int br = n0 + p * 32 + lrow;
        bok[p] = br < N;
        boff[p] = (size_t)br * K + lk;
    }
    for (int k0 = 0; k0 < K; k0 += 64) {
        uint4 av[4], bv[2];
        #pragma unroll
        for (int p = 0; p < 4; p++) av[p] = aok[p] ? *(const uint4*)(A + aoff[p] + k0) : (uint4){0,0,0,0};
        #pragma unroll
        for (int p = 0; p < 2; p++) bv[p] = bok[p] ? *(const uint4*)(Bt + boff[p] + k0) : (uint4){0,0,0,0};
        __syncthreads();
        #pragma unroll
        for (int p = 0; p < 4; p++) *(uint4*)&As[SWZ(p * 32 + lrow, lk)] = av[p];
        #pragma unroll
        for (int p = 0; p < 2; p++) *(uint4*)&Bs[SWZ(p * 32 + lrow, lk)] = bv[p];
        __syncthreads();
        #pragma unroll
        for (int ks = 0; ks < 2; ks++) {
            bf16x8 a[4], bb[2];
            #pragma unroll
            for (int i = 0; i < 4; i++) a[i] = *(const bf16x8*)&As[SWZ(wr * 64 + i * 16 + r, ks * 32 + g * 8)];
            #pragma unroll
            for (int j = 0; j < 2; j++) bb[j] = *(const bf16x8*)&Bs[SWZ(wc * 32 + j * 16 + r, ks * 32 + g * 8)];
            #pragma unroll
            for (int i = 0; i < 4; i++)
                #pragma unroll
                for (int j = 0; j < 2; j++)
                    acc[i][j] = __builtin_amdgcn_mfma_f32_16x16x32_bf16(a[i], bb[j], acc[i][j], 0, 0, 0);
        }
    }
    int Nh = N >> 1;
    #pragma unroll
    for (int i = 0; i < 4; i++)
        #pragma unroll
        for (int j = 0; j < 2; j++) {
            int col = n0 + wc * 32 + j * 16 + r;
            #pragma unroll
            for (int e = 0; e < 4; e++) {
                int row = m0 + wr * 64 + i * 16 + g * 4 + e;
                float v = acc[i][j][e];
                float o = __shfl_xor(v, 1);
                if (((r & 1) == 0) && row < M && col < N) {
                    float u = v, gg = o;
                    float sg = gg / (1.f + __expf(-gg));
                    act[(size_t)row * Nh + (col >> 1)] = f2bf(u * sg);
                }
            }
        }
}

// ------- split-bf16 (hi+lo, 3xMFMA) GEMM, 128x64 tile, BK=64 swizzled -------
__global__ __launch_bounds__(256) void gemm_x3(const unsigned short* __restrict__ Ah,
    const unsigned short* __restrict__ Al, const unsigned short* __restrict__ Bh,
    const unsigned short* __restrict__ Bl, float* __restrict__ C_, int M, int N, int K) {
    __shared__ unsigned short AsH[128 * 64], AsL[128 * 64], BsH[64 * 64], BsL[64 * 64];
    int m0 = blockIdx.x * 128, n0 = blockIdx.y * 64;
    int tid = threadIdx.x;
    int lane = tid & 63, wid = tid >> 6;
    int wr = wid >> 1, wc = wid & 1;
    int r = lane & 15, g = lane >> 4;
    int lrow = tid >> 3, lk = (tid & 7) * 8;
    f32x4 acc[4][2] = {};
    bool aok[4]; size_t aoff[4];
    #pragma unroll
    for (int p = 0; p < 4; p++) {
        int ar = m0 + p * 32 + lrow;
        aok[p] = ar < M;
        aoff[p] = (size_t)ar * K + lk;
    }
    bool bok[2]; size_t boff[2];
    #pragma unroll
    for (int p = 0; p < 2; p++) {
        int br = n0 + p * 32 + lrow;
        bok[p] = br < N;
        boff[p] = (size_t)br * K + lk;
    }
    for (int k0 = 0; k0 < K; k0 += 64) {
        uint4 avh[4], avl[4], bvh[2], bvl[2];
        #pragma unroll
        for (int p = 0; p < 4; p++) {
            avh[p] = aok[p] ? *(const uint4*)(Ah + aoff[p] + k0) : (uint4){0,0,0,0};
            avl[p] = aok[p] ? *(const uint4*)(Al + aoff[p] + k0) : (uint4){0,0,0,0};
        }
        #pragma unroll
        for (int p = 0; p < 2; p++) {
            bvh[p] = bok[p] ? *(const uint4*)(Bh + boff[p] + k0) : (uint4){0,0,0,0};
            bvl[p] = bok[p] ? *(const uint4*)(Bl + boff[p] + k0) : (uint4){0,0,0,0};
        }
        __syncthreads();
        #pragma unroll
        for (int p = 0; p < 4; p++) {
            *(uint4*)&AsH[SWZ(p * 32 + lrow, lk)] = avh[p];
            *(uint4*)&AsL[SWZ(p * 32 + lrow, lk)] = avl[p];
        }
        #pragma unroll
        for (int p = 0; p < 2; p++) {
            *(uint4*)&BsH[SWZ(p * 32 + lrow, lk)] = bvh[p];
            *(uint4*)&BsL[SWZ(p * 32 + lrow, lk)] = bvl[p];
        }
        __syncthreads();
        #pragma unroll
        for (int ks = 0; ks < 2; ks++) {
            bf16x8 ah[4], al[4], bh[2], bl[2];
            #pragma unroll
            for (int i = 0; i < 4; i++) {
                int ai = SWZ(wr * 64 + i * 16 + r, ks * 32 + g * 8);
                ah[i] = *(const bf16x8*)&AsH[ai];
                al[i] = *(const bf16x8*)&AsL[ai];
            }
            #pragma unroll
            for (int j = 0; j < 2; j++) {
                int bi = SWZ(wc * 32 + j * 16 + r, ks * 32 + g * 8);
                bh[j] = *(const bf16x8*)&BsH[bi];
                bl[j] = *(const bf16x8*)&BsL[bi];
            }
            #pragma unroll
            for (int i = 0; i < 4; i++)
                #pragma unroll
                for (int j = 0; j < 2; j++) {
                    acc[i][j] = __builtin_amdgcn_mfma_f32_16x16x32_bf16(al[i], bh[j], acc[i][j], 0, 0, 0);
                    acc[i][j] = __builtin_amdgcn_mfma_f32_16x16x32_bf16(ah[i], bl[j], acc[i][j], 0, 0, 0);
                    acc[i][j] = __builtin_amdgcn_mfma_f32_16x16x32_bf16(ah[i], bh[j], acc[i][j], 0, 0, 0);
                }
        }
    }
    #pragma unroll
    for (int i = 0; i < 4; i++)
        #pragma unroll
        for (int j = 0; j < 2; j++) {
            int col = n0 + wc * 32 + j * 16 + r;
            if (col >= N) continue;
            #pragma unroll
            for (int e = 0; e < 4; e++) {
                int row = m0 + wr * 64 + i * 16 + g * 4 + e;
                if (row < M) C_[(size_t)row * N + col] = acc[i][j][e];
            }
        }
}

// ---------------- assemble q/k heads (f16 hi/lo, RoPE applied, padded 48->64) ------
__global__ void assemble2(const float* __restrict__ qf_, const float* __restrict__ kvf,
    const float* __restrict__ cq, const float* __restrict__ freqs,
    _Float16* __restrict__ qgh, _Float16* __restrict__ qgl,
    _Float16* __restrict__ kgh, _Float16* __restrict__ kgl) {
    size_t idx = (size_t)blockIdx.x * 256 + threadIdx.x;
    const size_t total = (size_t)NB * H2N * NS_PAD * 32;
    if (idx >= total) return;
    int j2 = (int)(idx & 31);
    size_t t = idx >> 5;
    int s = (int)(t % NS_PAD); size_t r = t / NS_PAD;
    int sub = (int)(r & 1); r >>= 1;
    int h = (int)(r & 7); int b = (int)(r >> 3);
    float2 qv = make_float2(0.f, 0.f), kv2 = make_float2(0.f, 0.f);
    if (s < NS && j2 < 24) {
        size_t bs = (size_t)b * NS + s;
        if (j2 < 16) {
            const float* qp = qf_ + bs * 768 + h * 96 + sub * 32 + j2 * 2;
            qv = make_float2(qp[0], qp[1]);
            const float* kp = kvf + bs * 1024 + h * 128 + sub * 32 + j2 * 2;
            kv2 = make_float2(kp[0], kp[1]);
        } else {
            int i = j2 - 16;
            const float* qp = qf_ + bs * 768 + h * 96 + 64 + sub * 16 + 2 * i;
            float xr = qp[0], xi = qp[1];
            const float* kp = cq + bs * 672 + 256 + sub * 16 + 2 * i;
            float yr = kp[0], yi = kp[1];
            if (s == 0) {
                qv = make_float2(xr, xi);
                kv2 = make_float2(yr, yi);
            } else {
                int pos = (s - 1) % SEQN;
                float c = freqs[pos * 16 + 2 * i], sn = freqs[pos * 16 + 2 * i + 1];
                qv = make_float2(xr * c - xi * sn, xr * sn + xi * c);
                kv2 = make_float2(yr * c - yi * sn, yr * sn + yi * c);
            }
        }
    }
    _Float16 qx = (_Float16)qv.x, qy = (_Float16)qv.y;
    _Float16 kx = (_Float16)kv2.x, ky = (_Float16)kv2.y;
    qgh[idx * 2] = qx; qgh[idx * 2 + 1] = qy;
    kgh[idx * 2] = kx; kgh[idx * 2 + 1] = ky;
    qgl[idx * 2] = (_Float16)(qv.x - (float)qx); qgl[idx * 2 + 1] = (_Float16)(qv.y - (float)qy);
    kgl[idx * 2] = (_Float16)(kv2.x - (float)kx); kgl[idx * 2 + 1] = (_Float16)(kv2.y - (float)ky);
}

// ---------------- V transpose: kvf -> vt [ (b*8+h)*64 + d ][ NS_PAD ] f16 ----------------
__global__ __launch_bounds__(256) void vtrans(const float* __restrict__ kvf,
                                              _Float16* __restrict__ vt) {
    __shared__ float tile[64][65];
    int k0 = blockIdx.x * 64;
    int b = blockIdx.y >> 3, h = blockIdx.y & 7;
    int tid = threadIdx.x;
    int row = tid >> 2, cq_ = (tid & 3) * 16;
    for (int i = 0; i < 16; i++) {
        int key = k0 + row;
        tile[row][cq_ + i] = (key < NS)
            ? kvf[((size_t)(b * NS + key)) * 1024 + h * 128 + 64 + cq_ + i] : 0.f;
    }
    __syncthreads();
    int d = tid >> 2, kq = (tid & 3) * 16;
    for (int i = 0; i < 16; i++)
        vt[((size_t)((b * 8 + h) * 64 + d)) * NS_PAD + k0 + kq + i] = (_Float16)tile[kq + i][d];
}

// ------- fused chunk-sum + prefix: P4[bh][p][d] = prefix over p of sum_c v ----------
__global__ __launch_bounds__(256) void prefix2_k(const float* __restrict__ kvf,
                                                 float* __restrict__ P4) {
    __shared__ float tot[4][64];
    int bh = blockIdx.x; int b = bh >> 3, h = bh & 7;
    int d = threadIdx.x & 63, ps = threadIdx.x >> 6;
    int p0 = ps * 96;
    float run = 0.f;
    for (int i = 0; i < 96; i++) {
        int p = p0 + i;
        float s = 0.f;
        #pragma unroll
        for (int c = 0; c < 4; c++)
            s += kvf[((size_t)(b * NS + 1 + c * SEQN + p)) * 1024 + h * 128 + 64 + d];
        run += s;
        P4[((size_t)bh * SEQN + p) * 64 + d] = run;
    }
    tot[ps][d] = run;
    __syncthreads();
    if (ps > 0) {
        float off = 0.f;
        for (int j = 0; j < ps; j++) off += tot[j][d];
        for (int i = 0; i < 96; i++)
            P4[((size_t)bh * SEQN + p0 + i) * 64 + d] += off;
    }
}

// ------- flash differential attention: BARRIER-FREE (direct-from-global K/V frags) ----
// K/V MFMA B-fragments are contiguous 16B in kg/vt layouts -> no LDS staging, no
// __syncthreads in the k-loop; only a wave-local 2KB P buffer remains (8KB total).
__global__ __launch_bounds__(256) void flash_split(
    const _Float16* __restrict__ qgh, const _Float16* __restrict__ qgl,
    const _Float16* __restrict__ kgh, const _Float16* __restrict__ kgl,
    const _Float16* __restrict__ vt,
    float* __restrict__ Opart, float* __restrict__ zpart) {
    __shared__ _Float16 Pl[4][16 * 64];
    const int tile = blockIdx.x;
    const int h = blockIdx.y & 7, split = blockIdx.y >> 3;
    const int b = blockIdx.z;
    const int bh = b * 8 + h;
    const int qs0 = tile * 64;
    const int tid = threadIdx.x;
    const int wave = tid >> 6, lane = tid & 63;
    const int r = lane & 15, g = lane >> 4;
    const int qrow = qs0 + wave * 16;
    const size_t sh0 = (size_t)(bh * 2);

    f16x8 qfh[2][2], qfl[2][2];
    #pragma unroll
    for (int sub = 0; sub < 2; sub++)
        #pragma unroll
        for (int ks = 0; ks < 2; ks++) {
            size_t off = ((sh0 + sub) * NS_PAD + qrow + r) * 64 + ks * 32 + g * 8;
            qfh[sub][ks] = *(const f16x8*)(qgh + off);
            qfl[sub][ks] = *(const f16x8*)(qgl + off);
        }

    // per-lane base pointers for direct fragment loads
    const _Float16* khb[2], *klb[2];
    #pragma unroll
    for (int sub = 0; sub < 2; sub++) {
        size_t base = ((sh0 + sub) * NS_PAD + r) * 64 + g * 8;
        khb[sub] = kgh + base;
        klb[sub] = kgl + base;
    }
    const _Float16* vbp[4];
    #pragma unroll
    for (int dt = 0; dt < 4; dt++)
        vbp[dt] = vt + (size_t)(bh * 64 + dt * 16 + r) * NS_PAD + g * 8;

    float z0p[4] = {0.f,0.f,0.f,0.f}, g0p[4] = {0.f,0.f,0.f,0.f}, z1p[4] = {0.f,0.f,0.f,0.f};
    f32x4 O0[4], O1[4];
    #pragma unroll
    for (int e = 0; e < 4; e++) { O0[e] = (f32x4){0.f,0.f,0.f,0.f}; O1[e] = (f32x4){0.f,0.f,0.f,0.f}; }
    int qpos[4];
    #pragma unroll
    for (int e = 0; e < 4; e++) {
        int q = qrow + g * 4 + e;
        qpos[e] = (q == 0) ? -1 : (q - 1) % SEQN;
    }
    int lo = qs0 < 1 ? 1 : qs0;
    int hi = qs0 + 63 < NS - 1 ? qs0 + 63 : NS - 1;
    int maxpos = ((lo - 1) / SEQN != (hi - 1) / SEQN) ? (SEQN - 1) : (hi - 1) % SEQN;

    for (int c = 2 * split; c < 2 * split + 2; c++) {
        int nb = (c == 0) ? ((maxpos + 2 + 63) >> 6) : ((maxpos + 1 + 63) >> 6);
        int kstart = (c == 0) ? 0 : (c * SEQN + 1);
        int cbase = c * SEQN + 1;
        for (int j = 0; j < nb; j++) {
            int kbase = kstart + j * 64;

            // V fragments direct from global (shared by both chains)
            f16x8 bv[4][2];
            #pragma unroll
            for (int dt = 0; dt < 4; dt++)
                #pragma unroll
                for (int ks = 0; ks < 2; ks++)
                    bv[dt][ks] = *(const f16x8*)(vbp[dt] + kbase + ks * 32);

            bool um[4][4];
            #pragma unroll
            for (int t4 = 0; t4 < 4; t4++) {
                int kk2 = kbase + t4 * 16 + r;
                int rel = kk2 - cbase;
                #pragma unroll
                for (int e = 0; e < 4; e++)
                    um[e][t4] = (kk2 == 0) ||
                                ((unsigned)rel < (unsigned)SEQN && rel <= qpos[e]);
            }

            #pragma unroll
            for (int sub = 0; sub < 2; sub++) {
                const _Float16* kh = khb[sub] + (size_t)kbase * 64;
                const _Float16* kl = klb[sub] + (size_t)kbase * 64;
                f32x4 acc[4];
                #pragma unroll
                for (int t4 = 0; t4 < 4; t4++) acc[t4] = (f32x4){0.f,0.f,0.f,0.f};
                __builtin_amdgcn_s_setprio(1);
                #pragma unroll
                for (int t4 = 0; t4 < 4; t4++)
                    #pragma unroll
                    for (int ks = 0; ks < 2; ks++) {
                        f16x8 bkh = *(const f16x8*)(kh + t4 * 16 * 64 + ks * 32);
                        f16x8 bkl = *(const f16x8*)(kl + t4 * 16 * 64 + ks * 32);
                        acc[t4] = __builtin_amdgcn_mfma_f32_16x16x32_f16(qfl[sub][ks], bkh, acc[t4], 0, 0, 0);
                        acc[t4] = __builtin_amdgcn_mfma_f32_16x16x32_f16(qfh[sub][ks], bkl, acc[t4], 0, 0, 0);
                        acc[t4] = __builtin_amdgcn_mfma_f32_16x16x32_f16(qfh[sub][ks], bkh, acc[t4], 0, 0, 0);
                    }
                __builtin_amdgcn_s_setprio(0);
                #pragma unroll
                for (int e = 0; e < 4; e++) {
                    #pragma unroll
                    for (int t4 = 0; t4 < 4; t4++) {
                        float a = acc[t4][e];
                        float ef = exp2f(fabsf(a) * SC2);
                        float ev = um[e][t4] ? ef : 0.f;
                        float pvv = copysignf(ev, a);
                        if (sub == 0) { z0p[e] += ev; g0p[e] += pvv; }
                        else          { z1p[e] += ev; }
                        Pl[wave][SWZ(g * 4 + e, t4 * 16 + r)] = (_Float16)pvv;
                    }
                }
                __builtin_amdgcn_wave_barrier();
                f16x8 pa0 = *(const f16x8*)&Pl[wave][SWZ(r, g * 8)];
                f16x8 pa1 = *(const f16x8*)&Pl[wave][SWZ(r, 32 + g * 8)];
                __builtin_amdgcn_s_setprio(1);
                #pragma unroll
                for (int dt = 0; dt < 4; dt++) {
                    if (sub == 0) {
                        O0[dt] = __builtin_amdgcn_mfma_f32_16x16x32_f16(pa0, bv[dt][0], O0[dt], 0, 0, 0);
                        O0[dt] = __builtin_amdgcn_mfma_f32_16x16x32_f16(pa1, bv[dt][1], O0[dt], 0, 0, 0);
                    } else {
                        O1[dt] = __builtin_amdgcn_mfma_f32_16x16x32_f16(pa0, bv[dt][0], O1[dt], 0, 0, 0);
                        O1[dt] = __builtin_amdgcn_mfma_f32_16x16x32_f16(pa1, bv[dt][1], O1[dt], 0, 0, 0);
                    }
                }
                __builtin_amdgcn_s_setprio(0);
            }
        }
    }

    // write partials to this split's slot
    #pragma unroll
    for (int e = 0; e < 4; e++) {
        float z0 = z0p[e], g0 = g0p[e], z1 = z1p[e];
        #pragma unroll
        for (int o = 1; o < 16; o <<= 1) {
            z0 += __shfl_xor(z0, o); g0 += __shfl_xor(g0, o); z1 += __shfl_xor(z1, o);
        }
        int q = qrow + g * 4 + e;
        if (q < NS) {
            if (r == 0) {
                float* zp = zpart + (((size_t)split * 16 + bh) * NS + q) * 4;
                zp[0] = z0; zp[1] = g0; zp[2] = z1;
            }
            float* op = Opart + (((size_t)split * 16 + bh) * NS + q) * 128;
            #pragma unroll
            for (int dt = 0; dt < 4; dt++) {
                op[dt * 16 + r] = O0[dt][e];
                op[64 + dt * 16 + r] = O1[dt][e];
            }
        }
    }
}

// ------- combine partials: lambda (inline) + G-term + head rmsnorm -> o_n (bf16) -------
__global__ __launch_bounds__(256) void combine_attn(const float* __restrict__ Opart,
    const float* __restrict__ zpart, const float* __restrict__ kvf,
    const float* __restrict__ P4,
    const float* __restrict__ lq1, const float* __restrict__ lk1,
    const float* __restrict__ lq2, const float* __restrict__ lk2,
    const float* __restrict__ hw, unsigned short* __restrict__ o_n) {
    __shared__ float lamS;
    if (threadIdx.x < 32) {
        float p1 = lq1[threadIdx.x] * lk1[threadIdx.x];
        float p2 = lq2[threadIdx.x] * lk2[threadIdx.x];
        for (int o = 1; o < 32; o <<= 1) { p1 += __shfl_xor(p1, o); p2 += __shfl_xor(p2, o); }
        if (threadIdx.x == 0) lamS = expf(p1) - expf(p2) + 0.2f;
    }
    __syncthreads();
    float lam = lamS;
    int b = blockIdx.z, h = blockIdx.y, bh = b * 8 + h;
    int ql = threadIdx.x >> 2, dp = threadIdx.x & 3;
    int q = blockIdx.x * 64 + ql;
    bool ok = q < NS;
    int qc = ok ? q : 0;
    size_t i0 = ((size_t)0 * 16 + bh) * NS + qc;
    size_t i1 = ((size_t)1 * 16 + bh) * NS + qc;
    const float* za = zpart + i0 * 4;
    const float* zb = zpart + i1 * 4;
    float z0 = za[0] + zb[0], g0 = za[1] + zb[1], z1 = za[2] + zb[2];
    float iz0 = 1.f / z0;
    float l1 = lam / z1;
    float Gl = lam * g0 * iz0 * (1.f / (float)NS);
    int qpos = (q == 0) ? -1 : (q - 1) % SEQN;
    const float* oa = Opart + i0 * 128 + dp * 16;
    const float* ob = Opart + i1 * 128 + dp * 16;
    float of[16]; float ss = 0.f;
    #pragma unroll
    for (int i = 0; i < 16; i++) {
        int d = dp * 16 + i;
        float O0 = oa[i] + ob[i];
        float O1 = oa[64 + i] + ob[64 + i];
        float vs = kvf[((size_t)(b * NS)) * 1024 + h * 128 + 64 + d];
        if (qpos >= 0) vs += P4[((size_t)bh * SEQN + qpos) * 64 + d];
        float o = O0 * iz0 - O1 * l1 + Gl * vs;
        of[i] = o; ss += o * o;
    }
    ss += __shfl_xor(ss, 1); ss += __shfl_xor(ss, 2);
    float rs = rsqrtf(ss / 64.f + 1e-5f);
    if (ok) {
        unsigned int pk[8];
        #pragma unroll
        for (int i = 0; i < 8; i++) {
            unsigned int a = f2bf(of[2 * i] * rs * hw[dp * 16 + 2 * i]);
            unsigned int c = f2bf(of[2 * i + 1] * rs * hw[dp * 16 + 2 * i + 1]);
            pk[i] = a | (c << 16);
        }
        unsigned short* dst = o_n + ((size_t)(b * NS + q)) * 512 + h * 64 + dp * 16;
        *(uint4*)dst = *(uint4*)&pk[0];
        *(uint4*)(dst + 8) = *(uint4*)&pk[4];
    }
}

// ---------------- host ----------------
extern "C" void kernel_launch(void* const* d_in, const int* in_sizes, int n_in,
                              void* d_out, int out_size, void* d_ws, size_t ws_size,
                              hipStream_t stream) {
    (void)in_sizes; (void)n_in; (void)out_size; (void)ws_size;
    const float* x    = (const float*)d_in[0];
    const float* freqs= (const float*)d_in[1];
    const float* Wkvd = (const float*)d_in[2];
    const float* Wqd  = (const float*)d_in[3];
    const float* Wkvu = (const float*)d_in[4];
    const float* Wqu  = (const float*)d_in[5];
    const float* kvnw = (const float*)d_in[6];
    const float* qnw  = (const float*)d_in[7];
    const float* Wo   = (const float*)d_in[8];
    const float* lq1  = (const float*)d_in[9];
    const float* lk1  = (const float*)d_in[10];
    const float* lq2  = (const float*)d_in[11];
    const float* lk2  = (const float*)d_in[12];
    const float* hnw  = (const float*)d_in[13];
    const float* n1w  = (const float*)d_in[14];
    const float* n2w  = (const float*)d_in[15];
    const float* Wffi = (const float*)d_in[16];
    const float* Wffo = (const float*)d_in[17];
    float* out = (float*)d_out;

    char* p = (char*)d_ws;
    auto alloc = [&](size_t nbytes) -> char* {
        char* r = p; p += (nbytes + 255) & ~(size_t)255; return r;
    };
    // weights (wcq = combined Wkvd|Wqd, N=672)
    unsigned short* wcq_h  = (unsigned short*)alloc((size_t)672 * 512 * 2);
    unsigned short* wcq_l  = (unsigned short*)alloc((size_t)672 * 512 * 2);
    unsigned short* wkvu_h = (unsigned short*)alloc((size_t)256 * 1024 * 2);
    unsigned short* wkvu_l = (unsigned short*)alloc((size_t)256 * 1024 * 2);
    unsigned short* wqu_h  = (unsigned short*)alloc((size_t)384 * 768 * 2);
    unsigned short* wqu_l  = (unsigned short*)alloc((size_t)384 * 768 * 2);
    unsigned short* wo_h   = (unsigned short*)alloc((size_t)512 * 512 * 2);
    unsigned short* wffi_h = (unsigned short*)alloc((size_t)512 * 3072 * 2);
    unsigned short* wffo_h = (unsigned short*)alloc((size_t)1536 * 512 * 2);
    unsigned short* h_hi   = (unsigned short*)alloc((size_t)NM * 512 * 2);
    unsigned short* h_lo   = (unsigned short*)alloc((size_t)NM * 512 * 2);
    // cq (3074 x 672) — aliased later by x2
    char* cq0 = p;
    float* cq = (float*)alloc((size_t)NM * 672 * 4);
    float* x2 = (float*)cq0;
    // norm block — act aliases the front
    char* nb0_ = p;
    unsigned short* ckvn_h = (unsigned short*)alloc((size_t)NM * 256 * 2);
    unsigned short* ckvn_l = (unsigned short*)alloc((size_t)NM * 256 * 2);
    unsigned short* qdn_h  = (unsigned short*)alloc((size_t)NM * 384 * 2);
    unsigned short* qdn_l  = (unsigned short*)alloc((size_t)NM * 384 * 2);
    unsigned short* o_n    = (unsigned short*)alloc((size_t)NM * 512 * 2);
    unsigned short* h2     = (unsigned short*)alloc((size_t)NM * 512 * 2);
    unsigned short* act    = (unsigned short*)nb0_;
    // attention region
    float* kvf = (float*)alloc((size_t)NM * 1024 * 4);
    float* qff = (float*)alloc((size_t)NM * 768 * 4);
    _Float16* qgh = (_Float16*)alloc((size_t)NB * H2N * NS_PAD * 64 * 2);
    _Float16* qgl = (_Float16*)alloc((size_t)NB * H2N * NS_PAD * 64 * 2);
    _Float16* kgh = (_Float16*)alloc((size_t)NB * H2N * NS_PAD * 64 * 2);
    _Float16* kgl = (_Float16*)alloc((size_t)NB * H2N * NS_PAD * 64 * 2);
    _Float16* vt  = (_Float16*)alloc((size_t)NB * NH * 64 * NS_PAD * 2);
    float* P4     = (float*)alloc((size_t)NB * NH * SEQN * 64 * 4);
    float* Opart  = (float*)alloc((size_t)2 * 16 * NS * 128 * 4);
    float* zpart  = (float*)alloc((size_t)2 * 16 * NS * 4 * 4);

    // fused weight transposes (Wkvd/Wqd share wcq output; Wffi interleaved for swiglu)
    int cum = 0;
    {
        TD7 a;
        const float* ws_[7] = {Wkvd, Wqd, Wkvu, Wqu, Wo, Wffi, Wffo};
        unsigned short* his[7] = {wcq_h, wcq_h + (size_t)288 * 512, wkvu_h, wqu_h, wo_h, wffi_h, wffo_h};
        unsigned short* los[7] = {wcq_l, wcq_l + (size_t)288 * 512, wkvu_l, wqu_l, nullptr, nullptr, nullptr};
        int Ks[7] = {512, 512, 256, 384, 512, 512, 1536};
        int Ns[7] = {288, 384, 1024, 768, 512, 3072, 512};
        int pm[7] = {0, 0, 0, 0, 0, 1, 0};
        for (int i = 0; i < 7; i++) {
            a.d[i] = TD{ws_[i], his[i], los[i], Ks[i], Ns[i], pm[i]};
            cum += ((Ks[i] + 31) / 32) * ((Ns[i] + 31) / 32);
            a.tend[i] = cum;
        }
        transpose_all<<<dim3(cum), 256, 0, stream>>>(a);
    }

    rmsnorm_k<<<NM, 256, 0, stream>>>(x, n1w, h_hi, h_lo, 512, 512, EPS1);

    const int GX = (NM + 127) / 128;
    gemm_x3<<<dim3(GX, (672 + 63) / 64), 256, 0, stream>>>(h_hi, h_lo, wcq_h, wcq_l, cq, NM, 672, 512);

    rmsnorm_dual<<<NM, 256, 0, stream>>>(cq, kvnw, qnw, ckvn_h, ckvn_l, qdn_h, qdn_l);

    gemm_x3<<<dim3(GX, 1024 / 64), 256, 0, stream>>>(ckvn_h, ckvn_l, wkvu_h, wkvu_l, kvf, NM, 1024, 256);
    gemm_x3<<<dim3(GX, 768 / 64), 256, 0, stream>>>(qdn_h, qdn_l, wqu_h, wqu_l, qff, NM, 768, 384);

    {
        size_t total = (size_t)NB * H2N * NS_PAD * 32;
        assemble2<<<dim3((unsigned)((total + 255) / 256)), 256, 0, stream>>>(
            qff, kvf, cq, freqs, qgh, qgl, kgh, kgl);
    }
    vtrans<<<dim3(NS_PAD / 64, NB * NH), 256, 0, stream>>>(kvf, vt);
    prefix2_k<<<dim3(NB * NH), 256, 0, stream>>>(kvf, P4);

    flash_split<<<dim3((NS + 63) / 64, 16, NB), 256, 0, stream>>>(
        qgh, qgl, kgh, kgl, vt, Opart, zpart);
    combine_attn<<<dim3((NS + 63) / 64, NH, NB), 256, 0, stream>>>(
        Opart, zpart, kvf, P4, lq1, lk1, lq2, lk2, hnw, o_n);

    gemm_single<<<dim3(GX, 512 / 64), 256, 0, stream>>>(o_n, wo_h, x2, x, NM, 512, 512);
    rmsnorm_k<<<NM, 256, 0, stream>>>(x2, n2w, h2, nullptr, 512, 512, EPS1);
    gemm_swiglu<<<dim3(GX, 3072 / 64), 256, 0, stream>>>(h2, wffi_h, act, NM, 3072, 512);
    gemm_single<<<dim3(GX, 512 / 64), 256, 0, stream>>>(act, wffo_h, out, x2, NM, 512, 1536);
}

// Round 11
// 392.048 us; speedup vs baseline: 1.2550x; 1.2550x over previous
//
#include <hip/hip_runtime.h>

#define NB 2
#define SEQN 384
#define NS 1537
#define NS_PAD 1600
#define NH 8
#define H2N 16
#define NM (NB*NS)
#define DFF 1536
#define EPS1 1.1920929e-07f
#define SCAL (1.0f/48.0f)
#define SC2 (SCAL * 1.4426950408889634f)   // SCAL * log2(e), for exp2

// swizzled index into a [rows][64] 16-bit tile (16B-granule XOR swizzle)
#define SWZ(row, col) ((((row) << 6)) + ((col) ^ (((row) & 7) << 3)))

typedef __bf16 bf16x8 __attribute__((ext_vector_type(8)));
typedef _Float16 f16x8 __attribute__((ext_vector_type(8)));
typedef float f32x4 __attribute__((ext_vector_type(4)));

__device__ __forceinline__ unsigned short f2bf(float f) {
    unsigned int u = __builtin_bit_cast(unsigned int, f);
    u += 0x7FFFu + ((u >> 16) & 1u);
    return (unsigned short)(u >> 16);
}
__device__ __forceinline__ float bf2f(unsigned short h) {
    unsigned int u = ((unsigned int)h) << 16;
    return __builtin_bit_cast(float, u);
}

// ---------------- fused weight transpose (KxN f32 -> NxK bf16 hi[/lo]) ----------------
struct TD { const float* w; unsigned short* hi; unsigned short* lo; int K; int N; int perm; };
struct TD7 { TD d[7]; int tend[7]; };

__global__ __launch_bounds__(256) void transpose_all(TD7 a) {
    __shared__ float tile[32][33];
    int t = blockIdx.x;
    int i = 0;
    while (t >= a.tend[i]) i++;
    int base = (i == 0) ? 0 : a.tend[i - 1];
    int lt = t - base;
    const float* w = a.d[i].w;
    unsigned short* hi = a.d[i].hi;
    unsigned short* lo = a.d[i].lo;
    int K = a.d[i].K, N = a.d[i].N, perm = a.d[i].perm;
    int Nh = N >> 1;
    int kt = (K + 31) / 32;
    int k0 = (lt % kt) * 32, n0 = (lt / kt) * 32;
    int tx = threadIdx.x & 31, ty4 = (threadIdx.x >> 5) * 4;
    for (int q = 0; q < 4; q++) {
        int k = k0 + ty4 + q, n = n0 + tx;
        tile[ty4 + q][tx] = (k < K && n < N) ? w[(size_t)k * N + n] : 0.f;
    }
    __syncthreads();
    for (int q = 0; q < 4; q++) {
        int n = n0 + ty4 + q, k = k0 + tx;
        if (n < N && k < K) {
            float v = tile[tx][ty4 + q];
            unsigned short hb = f2bf(v);
            int n_out = perm ? ((n < Nh) ? 2 * n : 2 * (n - Nh) + 1) : n;
            size_t o = (size_t)n_out * K + k;
            hi[o] = hb;
            if (lo) lo[o] = f2bf(v - bf2f(hb));
        }
    }
}

// ---------------- rmsnorm (f32 in, bf16 hi[/lo] out) ----------------
__global__ __launch_bounds__(256) void rmsnorm_k(const float* __restrict__ in,
    const float* __restrict__ w, unsigned short* __restrict__ hi, unsigned short* __restrict__ lo,
    int in_stride, int C, float eps) {
    int row = blockIdx.x;
    const float* x = in + (size_t)row * in_stride;
    float ss = 0.f;
    for (int j = threadIdx.x; j < C; j += 256) { float v = x[j]; ss += v * v; }
    for (int o = 1; o < 64; o <<= 1) ss += __shfl_xor(ss, o);
    __shared__ float red[4];
    if ((threadIdx.x & 63) == 0) red[threadIdx.x >> 6] = ss;
    __syncthreads();
    ss = red[0] + red[1] + red[2] + red[3];
    float rs = rsqrtf(ss / (float)C + eps);
    for (int j = threadIdx.x; j < C; j += 256) {
        float y = x[j] * rs * w[j];
        unsigned short hb = f2bf(y);
        hi[(size_t)row * C + j] = hb;
        if (lo) lo[(size_t)row * C + j] = f2bf(y - bf2f(hb));
    }
}

// ---------------- dual rmsnorm: cq row -> ckvn (C=256) + qdn (C=384, cols 288..671) --
__global__ __launch_bounds__(256) void rmsnorm_dual(const float* __restrict__ cq,
    const float* __restrict__ wA, const float* __restrict__ wB,
    unsigned short* __restrict__ ah, unsigned short* __restrict__ al,
    unsigned short* __restrict__ bh_, unsigned short* __restrict__ bl_) {
    int row = blockIdx.x, tid = threadIdx.x;
    const float* xx = cq + (size_t)row * 672;
    __shared__ float red[4];
    float v = xx[tid & 255];
    float ss = v * v;
    for (int o = 1; o < 64; o <<= 1) ss += __shfl_xor(ss, o);
    if ((tid & 63) == 0) red[tid >> 6] = ss;
    __syncthreads();
    float tot = red[0] + red[1] + red[2] + red[3];
    float rs = rsqrtf(tot / 256.f + EPS1);
    float y = v * rs * wA[tid];
    unsigned short hb = f2bf(y);
    ah[(size_t)row * 256 + tid] = hb;
    al[(size_t)row * 256 + tid] = f2bf(y - bf2f(hb));
    __syncthreads();
    float v0 = xx[288 + tid];
    float v1 = (tid < 128) ? xx[288 + 256 + tid] : 0.f;
    float ss2 = v0 * v0 + v1 * v1;
    for (int o = 1; o < 64; o <<= 1) ss2 += __shfl_xor(ss2, o);
    if ((tid & 63) == 0) red[tid >> 6] = ss2;
    __syncthreads();
    tot = red[0] + red[1] + red[2] + red[3];
    rs = rsqrtf(tot / 384.f + EPS1);
    float yb = v0 * rs * wB[tid];
    hb = f2bf(yb);
    bh_[(size_t)row * 384 + tid] = hb;
    bl_[(size_t)row * 384 + tid] = f2bf(yb - bf2f(hb));
    if (tid < 128) {
        float yc = v1 * rs * wB[256 + tid];
        unsigned short hc = f2bf(yc);
        bh_[(size_t)row * 384 + 256 + tid] = hc;
        bl_[(size_t)row * 384 + 256 + tid] = f2bf(yc - bf2f(hc));
    }
}

// ------- single-bf16 GEMM, 128x64 tile, BK=64, swizzled LDS -------
__global__ __launch_bounds__(256) void gemm_single(const unsigned short* __restrict__ A,
    const unsigned short* __restrict__ Bt, float* __restrict__ C_, const float* __restrict__ res,
    int M, int N, int K) {
    __shared__ unsigned short As[128 * 64];
    __shared__ unsigned short Bs[64 * 64];
    int m0 = blockIdx.x * 128, n0 = blockIdx.y * 64;
    int tid = threadIdx.x;
    int lane = tid & 63, wid = tid >> 6;
    int wr = wid >> 1, wc = wid & 1;
    int r = lane & 15, g = lane >> 4;
    int lrow = tid >> 3, lk = (tid & 7) * 8;
    f32x4 acc[4][2] = {};
    bool aok[4]; size_t aoff[4];
    #pragma unroll
    for (int p = 0; p < 4; p++) {
        int ar = m0 + p * 32 + lrow;
        aok[p] = ar < M;
        aoff[p] = (size_t)ar * K + lk;
    }
    bool bok[2]; size_t boff[2];
    #pragma unroll
    for (int p = 0; p < 2; p++) {
        int br = n0 + p * 32 + lrow;
        bok[p] = br < N;
        boff[p] = (size_t)br * K + lk;
    }
    for (int k0 = 0; k0 < K; k0 += 64) {
        uint4 av[4], bv[2];
        #pragma unroll
        for (int p = 0; p < 4; p++) av[p] = aok[p] ? *(const uint4*)(A + aoff[p] + k0) : (uint4){0,0,0,0};
        #pragma unroll
        for (int p = 0; p < 2; p++) bv[p] = bok[p] ? *(const uint4*)(Bt + boff[p] + k0) : (uint4){0,0,0,0};
        __syncthreads();
        #pragma unroll
        for (int p = 0; p < 4; p++) *(uint4*)&As[SWZ(p * 32 + lrow, lk)] = av[p];
        #pragma unroll
        for (int p = 0; p < 2; p++) *(uint4*)&Bs[SWZ(p * 32 + lrow, lk)] = bv[p];
        __syncthreads();
        #pragma unroll
        for (int ks = 0; ks < 2; ks++) {
            bf16x8 a[4], bb[2];
            #pragma unroll
            for (int i = 0; i < 4; i++) a[i] = *(const bf16x8*)&As[SWZ(wr * 64 + i * 16 + r, ks * 32 + g * 8)];
            #pragma unroll
            for (int j = 0; j < 2; j++) bb[j] = *(const bf16x8*)&Bs[SWZ(wc * 32 + j * 16 + r, ks * 32 + g * 8)];
            #pragma unroll
            for (int i = 0; i < 4; i++)
                #pragma unroll
                for (int j = 0; j < 2; j++)
                    acc[i][j] = __builtin_amdgcn_mfma_f32_16x16x32_bf16(a[i], bb[j], acc[i][j], 0, 0, 0);
        }
    }
    #pragma unroll
    for (int i = 0; i < 4; i++)
        #pragma unroll
        for (int j = 0; j < 2; j++) {
            int col = n0 + wc * 32 + j * 16 + r;
            if (col >= N) continue;
            #pragma unroll
            for (int e = 0; e < 4; e++) {
                int row = m0 + wr * 64 + i * 16 + g * 4 + e;
                if (row >= M) continue;
                float v = acc[i][j][e];
                if (res) v += res[(size_t)row * N + col];
                C_[(size_t)row * N + col] = v;
            }
        }
}

// ------- GEMM + fused swiglu epilogue (interleaved u/g cols), BK=64 swizzled -------
__global__ __launch_bounds__(256) void gemm_swiglu(const unsigned short* __restrict__ A,
    const unsigned short* __restrict__ Bt, unsigned short* __restrict__ act,
    int M, int N, int K) {
    __shared__ unsigned short As[128 * 64];
    __shared__ unsigned short Bs[64 * 64];
    int m0 = blockIdx.x * 128, n0 = blockIdx.y * 64;
    int tid = threadIdx.x;
    int lane = tid & 63, wid = tid >> 6;
    int wr = wid >> 1, wc = wid & 1;
    int r = lane & 15, g = lane >> 4;
    int lrow = tid >> 3, lk = (tid & 7) * 8;
    f32x4 acc[4][2] = {};
    bool aok[4]; size_t aoff[4];
    #pragma unroll
    for (int p = 0; p < 4; p++) {
        int ar = m0 + p * 32 + lrow;
        aok[p] = ar < M;
        aoff[p] = (size_t)ar * K + lk;
    }
    bool bok[2]; size_t boff[2];
    #pragma unroll
    for (int p = 0; p < 2; p++) {
        int br = n0 + p * 32 + lrow;
        bok[p] = br < N;
        boff[p] = (size_t)br * K + lk;
    }
    for (int k0 = 0; k0 < K; k0 += 64) {
        uint4 av[4], bv[2];
        #pragma unroll
        for (int p = 0; p < 4; p++) av[p] = aok[p] ? *(const uint4*)(A + aoff[p] + k0) : (uint4){0,0,0,0};
        #pragma unroll
        for (int p = 0; p < 2; p++) bv[p] = bok[p] ? *(const uint4*)(Bt + boff[p] + k0) : (uint4){0,0,0,0};
        __syncthreads();
        #pragma unroll
        for (int p = 0; p < 4; p++) *(uint4*)&As[SWZ(p * 32 + lrow, lk)] = av[p];
        #pragma unroll
        for (int p = 0; p < 2; p++) *(uint4*)&Bs[SWZ(p * 32 + lrow, lk)] = bv[p];
        __syncthreads();
        #pragma unroll
        for (int ks = 0; ks < 2; ks++) {
            bf16x8 a[4], bb[2];
            #pragma unroll
            for (int i = 0; i < 4; i++) a[i] = *(const bf16x8*)&As[SWZ(wr * 64 + i * 16 + r, ks * 32 + g * 8)];
            #pragma unroll
            for (int j = 0; j < 2; j++) bb[j] = *(const bf16x8*)&Bs[SWZ(wc * 32 + j * 16 + r, ks * 32 + g * 8)];
            #pragma unroll
            for (int i = 0; i < 4; i++)
                #pragma unroll
                for (int j = 0; j < 2; j++)
                    acc[i][j] = __builtin_amdgcn_mfma_f32_16x16x32_bf16(a[i], bb[j], acc[i][j], 0, 0, 0);
        }
    }
    int Nh = N >> 1;
    #pragma unroll
    for (int i = 0; i < 4; i++)
        #pragma unroll
        for (int j = 0; j < 2; j++) {
            int col = n0 + wc * 32 + j * 16 + r;
            #pragma unroll
            for (int e = 0; e < 4; e++) {
                int row = m0 + wr * 64 + i * 16 + g * 4 + e;
                float v = acc[i][j][e];
                float o = __shfl_xor(v, 1);
                if (((r & 1) == 0) && row < M && col < N) {
                    float u = v, gg = o;
                    float sg = gg / (1.f + __expf(-gg));
                    act[(size_t)row * Nh + (col >> 1)] = f2bf(u * sg);
                }
            }
        }
}

// ------- split-bf16 (hi+lo, 3xMFMA) GEMM, 128x64 tile, BK=64 swizzled -------
__global__ __launch_bounds__(256) void gemm_x3(const unsigned short* __restrict__ Ah,
    const unsigned short* __restrict__ Al, const unsigned short* __restrict__ Bh,
    const unsigned short* __restrict__ Bl, float* __restrict__ C_, int M, int N, int K) {
    __shared__ unsigned short AsH[128 * 64], AsL[128 * 64], BsH[64 * 64], BsL[64 * 64];
    int m0 = blockIdx.x * 128, n0 = blockIdx.y * 64;
    int tid = threadIdx.x;
    int lane = tid & 63, wid = tid >> 6;
    int wr = wid >> 1, wc = wid & 1;
    int r = lane & 15, g = lane >> 4;
    int lrow = tid >> 3, lk = (tid & 7) * 8;
    f32x4 acc[4][2] = {};
    bool aok[4]; size_t aoff[4];
    #pragma unroll
    for (int p = 0; p < 4; p++) {
        int ar = m0 + p * 32 + lrow;
        aok[p] = ar < M;
        aoff[p] = (size_t)ar * K + lk;
    }
    bool bok[2]; size_t boff[2];
    #pragma unroll
    for (int p = 0; p < 2; p++) {
        int br = n0 + p * 32 + lrow;
        bok[p] = br < N;
        boff[p] = (size_t)br * K + lk;
    }
    for (int k0 = 0; k0 < K; k0 += 64) {
        uint4 avh[4], avl[4], bvh[2], bvl[2];
        #pragma unroll
        for (int p = 0; p < 4; p++) {
            avh[p] = aok[p] ? *(const uint4*)(Ah + aoff[p] + k0) : (uint4){0,0,0,0};
            avl[p] = aok[p] ? *(const uint4*)(Al + aoff[p] + k0) : (uint4){0,0,0,0};
        }
        #pragma unroll
        for (int p = 0; p < 2; p++) {
            bvh[p] = bok[p] ? *(const uint4*)(Bh + boff[p] + k0) : (uint4){0,0,0,0};
            bvl[p] = bok[p] ? *(const uint4*)(Bl + boff[p] + k0) : (uint4){0,0,0,0};
        }
        __syncthreads();
        #pragma unroll
        for (int p = 0; p < 4; p++) {
            *(uint4*)&AsH[SWZ(p * 32 + lrow, lk)] = avh[p];
            *(uint4*)&AsL[SWZ(p * 32 + lrow, lk)] = avl[p];
        }
        #pragma unroll
        for (int p = 0; p < 2; p++) {
            *(uint4*)&BsH[SWZ(p * 32 + lrow, lk)] = bvh[p];
            *(uint4*)&BsL[SWZ(p * 32 + lrow, lk)] = bvl[p];
        }
        __syncthreads();
        #pragma unroll
        for (int ks = 0; ks < 2; ks++) {
            bf16x8 ah[4], al[4], bh[2], bl[2];
            #pragma unroll
            for (int i = 0; i < 4; i++) {
                int ai = SWZ(wr * 64 + i * 16 + r, ks * 32 + g * 8);
                ah[i] = *(const bf16x8*)&AsH[ai];
                al[i] = *(const bf16x8*)&AsL[ai];
            }
            #pragma unroll
            for (int j = 0; j < 2; j++) {
                int bi = SWZ(wc * 32 + j * 16 + r, ks * 32 + g * 8);
                bh[j] = *(const bf16x8*)&BsH[bi];
                bl[j] = *(const bf16x8*)&BsL[bi];
            }
            #pragma unroll
            for (int i = 0; i < 4; i++)
                #pragma unroll
                for (int j = 0; j < 2; j++) {
                    acc[i][j] = __builtin_amdgcn_mfma_f32_16x16x32_bf16(al[i], bh[j], acc[i][j], 0, 0, 0);
                    acc[i][j] = __builtin_amdgcn_mfma_f32_16x16x32_bf16(ah[i], bl[j], acc[i][j], 0, 0, 0);
                    acc[i][j] = __builtin_amdgcn_mfma_f32_16x16x32_bf16(ah[i], bh[j], acc[i][j], 0, 0, 0);
                }
        }
    }
    #pragma unroll
    for (int i = 0; i < 4; i++)
        #pragma unroll
        for (int j = 0; j < 2; j++) {
            int col = n0 + wc * 32 + j * 16 + r;
            if (col >= N) continue;
            #pragma unroll
            for (int e = 0; e < 4; e++) {
                int row = m0 + wr * 64 + i * 16 + g * 4 + e;
                if (row < M) C_[(size_t)row * N + col] = acc[i][j][e];
            }
        }
}

// ---------------- assemble q/k heads (f16 hi/lo, RoPE applied, padded 48->64) ------
__global__ void assemble2(const float* __restrict__ qf_, const float* __restrict__ kvf,
    const float* __restrict__ cq, const float* __restrict__ freqs,
    _Float16* __restrict__ qgh, _Float16* __restrict__ qgl,
    _Float16* __restrict__ kgh, _Float16* __restrict__ kgl) {
    size_t idx = (size_t)blockIdx.x * 256 + threadIdx.x;
    const size_t total = (size_t)NB * H2N * NS_PAD * 32;
    if (idx >= total) return;
    int j2 = (int)(idx & 31);
    size_t t = idx >> 5;
    int s = (int)(t % NS_PAD); size_t r = t / NS_PAD;
    int sub = (int)(r & 1); r >>= 1;
    int h = (int)(r & 7); int b = (int)(r >> 3);
    float2 qv = make_float2(0.f, 0.f), kv2 = make_float2(0.f, 0.f);
    if (s < NS && j2 < 24) {
        size_t bs = (size_t)b * NS + s;
        if (j2 < 16) {
            const float* qp = qf_ + bs * 768 + h * 96 + sub * 32 + j2 * 2;
            qv = make_float2(qp[0], qp[1]);
            const float* kp = kvf + bs * 1024 + h * 128 + sub * 32 + j2 * 2;
            kv2 = make_float2(kp[0], kp[1]);
        } else {
            int i = j2 - 16;
            const float* qp = qf_ + bs * 768 + h * 96 + 64 + sub * 16 + 2 * i;
            float xr = qp[0], xi = qp[1];
            const float* kp = cq + bs * 672 + 256 + sub * 16 + 2 * i;
            float yr = kp[0], yi = kp[1];
            if (s == 0) {
                qv = make_float2(xr, xi);
                kv2 = make_float2(yr, yi);
            } else {
                int pos = (s - 1) % SEQN;
                float c = freqs[pos * 16 + 2 * i], sn = freqs[pos * 16 + 2 * i + 1];
                qv = make_float2(xr * c - xi * sn, xr * sn + xi * c);
                kv2 = make_float2(yr * c - yi * sn, yr * sn + yi * c);
            }
        }
    }
    _Float16 qx = (_Float16)qv.x, qy = (_Float16)qv.y;
    _Float16 kx = (_Float16)kv2.x, ky = (_Float16)kv2.y;
    qgh[idx * 2] = qx; qgh[idx * 2 + 1] = qy;
    kgh[idx * 2] = kx; kgh[idx * 2 + 1] = ky;
    qgl[idx * 2] = (_Float16)(qv.x - (float)qx); qgl[idx * 2 + 1] = (_Float16)(qv.y - (float)qy);
    kgl[idx * 2] = (_Float16)(kv2.x - (float)kx); kgl[idx * 2 + 1] = (_Float16)(kv2.y - (float)ky);
}

// ---------------- V transpose: kvf -> vt [ (b*8+h)*64 + d ][ NS_PAD ] f16 ----------------
__global__ __launch_bounds__(256) void vtrans(const float* __restrict__ kvf,
                                              _Float16* __restrict__ vt) {
    __shared__ float tile[64][65];
    int k0 = blockIdx.x * 64;
    int b = blockIdx.y >> 3, h = blockIdx.y & 7;
    int tid = threadIdx.x;
    int row = tid >> 2, cq_ = (tid & 3) * 16;
    for (int i = 0; i < 16; i++) {
        int key = k0 + row;
        tile[row][cq_ + i] = (key < NS)
            ? kvf[((size_t)(b * NS + key)) * 1024 + h * 128 + 64 + cq_ + i] : 0.f;
    }
    __syncthreads();
    int d = tid >> 2, kq = (tid & 3) * 16;
    for (int i = 0; i < 16; i++)
        vt[((size_t)((b * 8 + h) * 64 + d)) * NS_PAD + k0 + kq + i] = (_Float16)tile[kq + i][d];
}

// ------- fused chunk-sum + prefix: P4[bh][p][d] = prefix over p of sum_c v ----------
__global__ __launch_bounds__(256) void prefix2_k(const float* __restrict__ kvf,
                                                 float* __restrict__ P4) {
    __shared__ float tot[4][64];
    int bh = blockIdx.x; int b = bh >> 3, h = bh & 7;
    int d = threadIdx.x & 63, ps = threadIdx.x >> 6;
    int p0 = ps * 96;
    float run = 0.f;
    for (int i = 0; i < 96; i++) {
        int p = p0 + i;
        float s = 0.f;
        #pragma unroll
        for (int c = 0; c < 4; c++)
            s += kvf[((size_t)(b * NS + 1 + c * SEQN + p)) * 1024 + h * 128 + 64 + d];
        run += s;
        P4[((size_t)bh * SEQN + p) * 64 + d] = run;
    }
    tot[ps][d] = run;
    __syncthreads();
    if (ps > 0) {
        float off = 0.f;
        for (int j = 0; j < ps; j++) off += tot[j][d];
        for (int i = 0; i < 96; i++)
            P4[((size_t)bh * SEQN + p0 + i) * 64 + d] += off;
    }
}

// ------- flash differential attention: LDS-staged + T14 async prefetch ----
// Loads for tile t+1 are issued right after the barrier; compute of tile t hides
// their latency; reg->LDS write happens at the top of the next iteration.
__global__ __launch_bounds__(256) void flash_split(
    const _Float16* __restrict__ qgh, const _Float16* __restrict__ qgl,
    const _Float16* __restrict__ kgh, const _Float16* __restrict__ kgl,
    const _Float16* __restrict__ vt,
    float* __restrict__ Opart, float* __restrict__ zpart) {
    __shared__ _Float16 Ksh[2][64 * 64];
    __shared__ _Float16 Ksl[2][64 * 64];
    __shared__ _Float16 Vt[64 * 64];
    __shared__ _Float16 Pl[4][16 * 64];
    const int tile = blockIdx.x;
    const int h = blockIdx.y & 7, split = blockIdx.y >> 3;
    const int b = blockIdx.z;
    const int bh = b * 8 + h;
    const int qs0 = tile * 64;
    const int tid = threadIdx.x;
    const int wave = tid >> 6, lane = tid & 63;
    const int r = lane & 15, g = lane >> 4;
    const int qrow = qs0 + wave * 16;
    const size_t sh0 = (size_t)(bh * 2);

    f16x8 qfh[2][2], qfl[2][2];
    #pragma unroll
    for (int sub = 0; sub < 2; sub++)
        #pragma unroll
        for (int ks = 0; ks < 2; ks++) {
            size_t off = ((sh0 + sub) * NS_PAD + qrow + r) * 64 + ks * 32 + g * 8;
            qfh[sub][ks] = *(const f16x8*)(qgh + off);
            qfl[sub][ks] = *(const f16x8*)(qgl + off);
        }

    float z0p[4] = {0.f,0.f,0.f,0.f}, g0p[4] = {0.f,0.f,0.f,0.f}, z1p[4] = {0.f,0.f,0.f,0.f};
    f32x4 O0[4], O1[4];
    #pragma unroll
    for (int e = 0; e < 4; e++) { O0[e] = (f32x4){0.f,0.f,0.f,0.f}; O1[e] = (f32x4){0.f,0.f,0.f,0.f}; }
    int qpos[4];
    #pragma unroll
    for (int e = 0; e < 4; e++) {
        int q = qrow + g * 4 + e;
        qpos[e] = (q == 0) ? -1 : (q - 1) % SEQN;
    }
    int lo = qs0 < 1 ? 1 : qs0;
    int hi = qs0 + 63 < NS - 1 ? qs0 + 63 : NS - 1;
    int maxpos = ((lo - 1) / SEQN != (hi - 1) / SEQN) ? (SEQN - 1) : (hi - 1) % SEQN;

    // tile enumeration for this split (contiguous chunk pair)
    int nbs[2], kstarts[2];
    #pragma unroll
    for (int ci = 0; ci < 2; ci++) {
        int c = 2 * split + ci;
        nbs[ci] = (c == 0) ? ((maxpos + 2 + 63) >> 6) : ((maxpos + 1 + 63) >> 6);
        kstarts[ci] = (c == 0) ? 0 : (c * SEQN + 1);
    }
    int ntiles = nbs[0] + nbs[1];

    // per-thread staging geometry (constant across tiles)
    int larr[4], lrow4[4], lc8[4];
    #pragma unroll
    for (int i = 0; i < 4; i++) {
        int chunk = i * 256 + tid;
        larr[i] = chunk >> 9;
        int cc = chunk & 511;
        lrow4[i] = cc >> 3; lc8[i] = (cc & 7) * 8;
    }
    int vd[2], vc8[2];
    #pragma unroll
    for (int i = 0; i < 2; i++) {
        int cc = i * 256 + tid;
        vd[i] = cc >> 3; vc8[i] = (cc & 7) * 8;
    }

    uint4 pk[8], pv[2];
    auto kb_of = [&](int t, int& cbase) -> int {
        int ci = (t < nbs[0]) ? 0 : 1;
        int j = (ci == 0) ? t : (t - nbs[0]);
        cbase = (2 * split + ci) * SEQN + 1;
        return kstarts[ci] + j * 64;
    };
    auto issue = [&](int kbase) {
        #pragma unroll
        for (int i = 0; i < 4; i++) {
            size_t goff = ((sh0 + larr[i]) * NS_PAD + kbase + lrow4[i]) * 64 + lc8[i];
            pk[2 * i]     = *(const uint4*)(kgh + goff);
            pk[2 * i + 1] = *(const uint4*)(kgl + goff);
        }
        #pragma unroll
        for (int i = 0; i < 2; i++)
            pv[i] = *(const uint4*)(vt + ((size_t)(bh * 64 + vd[i])) * NS_PAD + kbase + vc8[i]);
    };

    { int cb; issue(kb_of(0, cb)); }

    for (int t = 0; t < ntiles; t++) {
        int cbase; int kbase = kb_of(t, cbase);
        __syncthreads();   // previous tile's compute done; safe to overwrite LDS
        #pragma unroll
        for (int i = 0; i < 4; i++) {
            int di = SWZ(lrow4[i], lc8[i]);
            *(uint4*)&Ksh[larr[i]][di] = pk[2 * i];
            *(uint4*)&Ksl[larr[i]][di] = pk[2 * i + 1];
        }
        #pragma unroll
        for (int i = 0; i < 2; i++)
            *(uint4*)&Vt[SWZ(vd[i], vc8[i])] = pv[i];
        __syncthreads();   // LDS writes visible
        if (t + 1 < ntiles) { int cbn; issue(kb_of(t + 1, cbn)); }  // prefetch next tile

        f16x8 bv[4][2];
        #pragma unroll
        for (int dt = 0; dt < 4; dt++)
            #pragma unroll
            for (int ks = 0; ks < 2; ks++)
                bv[dt][ks] = *(const f16x8*)&Vt[SWZ(dt * 16 + r, ks * 32 + g * 8)];

        bool um[4][4];
        #pragma unroll
        for (int t4 = 0; t4 < 4; t4++) {
            int kk2 = kbase + t4 * 16 + r;
            int rel = kk2 - cbase;
            #pragma unroll
            for (int e = 0; e < 4; e++)
                um[e][t4] = (kk2 == 0) ||
                            ((unsigned)rel < (unsigned)SEQN && rel <= qpos[e]);
        }

        #pragma unroll
        for (int sub = 0; sub < 2; sub++) {
            f32x4 acc[4];
            #pragma unroll
            for (int t4 = 0; t4 < 4; t4++) acc[t4] = (f32x4){0.f,0.f,0.f,0.f};
            __builtin_amdgcn_s_setprio(1);
            #pragma unroll
            for (int t4 = 0; t4 < 4; t4++)
                #pragma unroll
                for (int ks = 0; ks < 2; ks++) {
                    int ki = SWZ(t4 * 16 + r, ks * 32 + g * 8);
                    f16x8 bkh = *(const f16x8*)&Ksh[sub][ki];
                    f16x8 bkl = *(const f16x8*)&Ksl[sub][ki];
                    acc[t4] = __builtin_amdgcn_mfma_f32_16x16x32_f16(qfl[sub][ks], bkh, acc[t4], 0, 0, 0);
                    acc[t4] = __builtin_amdgcn_mfma_f32_16x16x32_f16(qfh[sub][ks], bkl, acc[t4], 0, 0, 0);
                    acc[t4] = __builtin_amdgcn_mfma_f32_16x16x32_f16(qfh[sub][ks], bkh, acc[t4], 0, 0, 0);
                }
            __builtin_amdgcn_s_setprio(0);
            #pragma unroll
            for (int e = 0; e < 4; e++) {
                #pragma unroll
                for (int t4 = 0; t4 < 4; t4++) {
                    float a = acc[t4][e];
                    float ef = exp2f(fabsf(a) * SC2);
                    float ev = um[e][t4] ? ef : 0.f;
                    float pvv = copysignf(ev, a);
                    if (sub == 0) { z0p[e] += ev; g0p[e] += pvv; }
                    else          { z1p[e] += ev; }
                    Pl[wave][SWZ(g * 4 + e, t4 * 16 + r)] = (_Float16)pvv;
                }
            }
            __builtin_amdgcn_wave_barrier();
            f16x8 pa0 = *(const f16x8*)&Pl[wave][SWZ(r, g * 8)];
            f16x8 pa1 = *(const f16x8*)&Pl[wave][SWZ(r, 32 + g * 8)];
            __builtin_amdgcn_s_setprio(1);
            #pragma unroll
            for (int dt = 0; dt < 4; dt++) {
                if (sub == 0) {
                    O0[dt] = __builtin_amdgcn_mfma_f32_16x16x32_f16(pa0, bv[dt][0], O0[dt], 0, 0, 0);
                    O0[dt] = __builtin_amdgcn_mfma_f32_16x16x32_f16(pa1, bv[dt][1], O0[dt], 0, 0, 0);
                } else {
                    O1[dt] = __builtin_amdgcn_mfma_f32_16x16x32_f16(pa0, bv[dt][0], O1[dt], 0, 0, 0);
                    O1[dt] = __builtin_amdgcn_mfma_f32_16x16x32_f16(pa1, bv[dt][1], O1[dt], 0, 0, 0);
                }
            }
            __builtin_amdgcn_s_setprio(0);
        }
    }

    // write partials to this split's slot
    #pragma unroll
    for (int e = 0; e < 4; e++) {
        float z0 = z0p[e], g0 = g0p[e], z1 = z1p[e];
        #pragma unroll
        for (int o = 1; o < 16; o <<= 1) {
            z0 += __shfl_xor(z0, o); g0 += __shfl_xor(g0, o); z1 += __shfl_xor(z1, o);
        }
        int q = qrow + g * 4 + e;
        if (q < NS) {
            if (r == 0) {
                float* zp = zpart + (((size_t)split * 16 + bh) * NS + q) * 4;
                zp[0] = z0; zp[1] = g0; zp[2] = z1;
            }
            float* op = Opart + (((size_t)split * 16 + bh) * NS + q) * 128;
            #pragma unroll
            for (int dt = 0; dt < 4; dt++) {
                op[dt * 16 + r] = O0[dt][e];
                op[64 + dt * 16 + r] = O1[dt][e];
            }
        }
    }
}

// ------- combine partials: lambda (inline) + G-term + head rmsnorm -> o_n (bf16) -------
__global__ __launch_bounds__(256) void combine_attn(const float* __restrict__ Opart,
    const float* __restrict__ zpart, const float* __restrict__ kvf,
    const float* __restrict__ P4,
    const float* __restrict__ lq1, const float* __restrict__ lk1,
    const float* __restrict__ lq2, const float* __restrict__ lk2,
    const float* __restrict__ hw, unsigned short* __restrict__ o_n) {
    __shared__ float lamS;
    if (threadIdx.x < 32) {
        float p1 = lq1[threadIdx.x] * lk1[threadIdx.x];
        float p2 = lq2[threadIdx.x] * lk2[threadIdx.x];
        for (int o = 1; o < 32; o <<= 1) { p1 += __shfl_xor(p1, o); p2 += __shfl_xor(p2, o); }
        if (threadIdx.x == 0) lamS = expf(p1) - expf(p2) + 0.2f;
    }
    __syncthreads();
    float lam = lamS;
    int b = blockIdx.z, h = blockIdx.y, bh = b * 8 + h;
    int ql = threadIdx.x >> 2, dp = threadIdx.x & 3;
    int q = blockIdx.x * 64 + ql;
    bool ok = q < NS;
    int qc = ok ? q : 0;
    size_t i0 = ((size_t)0 * 16 + bh) * NS + qc;
    size_t i1 = ((size_t)1 * 16 + bh) * NS + qc;
    const float* za = zpart + i0 * 4;
    const float* zb = zpart + i1 * 4;
    float z0 = za[0] + zb[0], g0 = za[1] + zb[1], z1 = za[2] + zb[2];
    float iz0 = 1.f / z0;
    float l1 = lam / z1;
    float Gl = lam * g0 * iz0 * (1.f / (float)NS);
    int qpos = (q == 0) ? -1 : (q - 1) % SEQN;
    const float* oa = Opart + i0 * 128 + dp * 16;
    const float* ob = Opart + i1 * 128 + dp * 16;
    float of[16]; float ss = 0.f;
    #pragma unroll
    for (int i = 0; i < 16; i++) {
        int d = dp * 16 + i;
        float O0 = oa[i] + ob[i];
        float O1 = oa[64 + i] + ob[64 + i];
        float vs = kvf[((size_t)(b * NS)) * 1024 + h * 128 + 64 + d];
        if (qpos >= 0) vs += P4[((size_t)bh * SEQN + qpos) * 64 + d];
        float o = O0 * iz0 - O1 * l1 + Gl * vs;
        of[i] = o; ss += o * o;
    }
    ss += __shfl_xor(ss, 1); ss += __shfl_xor(ss, 2);
    float rs = rsqrtf(ss / 64.f + 1e-5f);
    if (ok) {
        unsigned int pk[8];
        #pragma unroll
        for (int i = 0; i < 8; i++) {
            unsigned int a = f2bf(of[2 * i] * rs * hw[dp * 16 + 2 * i]);
            unsigned int c = f2bf(of[2 * i + 1] * rs * hw[dp * 16 + 2 * i + 1]);
            pk[i] = a | (c << 16);
        }
        unsigned short* dst = o_n + ((size_t)(b * NS + q)) * 512 + h * 64 + dp * 16;
        *(uint4*)dst = *(uint4*)&pk[0];
        *(uint4*)(dst + 8) = *(uint4*)&pk[4];
    }
}

// ---------------- host ----------------
extern "C" void kernel_launch(void* const* d_in, const int* in_sizes, int n_in,
                              void* d_out, int out_size, void* d_ws, size_t ws_size,
                              hipStream_t stream) {
    (void)in_sizes; (void)n_in; (void)out_size; (void)ws_size;
    const float* x    = (const float*)d_in[0];
    const float* freqs= (const float*)d_in[1];
    const float* Wkvd = (const float*)d_in[2];
    const float* Wqd  = (const float*)d_in[3];
    const float* Wkvu = (const float*)d_in[4];
    const float* Wqu  = (const float*)d_in[5];
    const float* kvnw = (const float*)d_in[6];
    const float* qnw  = (const float*)d_in[7];
    const float* Wo   = (const float*)d_in[8];
    const float* lq1  = (const float*)d_in[9];
    const float* lk1  = (const float*)d_in[10];
    const float* lq2  = (const float*)d_in[11];
    const float* lk2  = (const float*)d_in[12];
    const float* hnw  = (const float*)d_in[13];
    const float* n1w  = (const float*)d_in[14];
    const float* n2w  = (const float*)d_in[15];
    const float* Wffi = (const float*)d_in[16];
    const float* Wffo = (const float*)d_in[17];
    float* out = (float*)d_out;

    char* p = (char*)d_ws;
    auto alloc = [&](size_t nbytes) -> char* {
        char* r = p; p += (nbytes + 255) & ~(size_t)255; return r;
    };
    // weights (wcq = combined Wkvd|Wqd, N=672)
    unsigned short* wcq_h  = (unsigned short*)alloc((size_t)672 * 512 * 2);
    unsigned short* wcq_l  = (unsigned short*)alloc((size_t)672 * 512 * 2);
    unsigned short* wkvu_h = (unsigned short*)alloc((size_t)256 * 1024 * 2);
    unsigned short* wkvu_l = (unsigned short*)alloc((size_t)256 * 1024 * 2);
    unsigned short* wqu_h  = (unsigned short*)alloc((size_t)384 * 768 * 2);
    unsigned short* wqu_l  = (unsigned short*)alloc((size_t)384 * 768 * 2);
    unsigned short* wo_h   = (unsigned short*)alloc((size_t)512 * 512 * 2);
    unsigned short* wffi_h = (unsigned short*)alloc((size_t)512 * 3072 * 2);
    unsigned short* wffo_h = (unsigned short*)alloc((size_t)1536 * 512 * 2);
    unsigned short* h_hi   = (unsigned short*)alloc((size_t)NM * 512 * 2);
    unsigned short* h_lo   = (unsigned short*)alloc((size_t)NM * 512 * 2);
    // cq (3074 x 672) — aliased later by x2
    char* cq0 = p;
    float* cq = (float*)alloc((size_t)NM * 672 * 4);
    float* x2 = (float*)cq0;
    // norm block — act aliases the front
    char* nb0_ = p;
    unsigned short* ckvn_h = (unsigned short*)alloc((size_t)NM * 256 * 2);
    unsigned short* ckvn_l = (unsigned short*)alloc((size_t)NM * 256 * 2);
    unsigned short* qdn_h  = (unsigned short*)alloc((size_t)NM * 384 * 2);
    unsigned short* qdn_l  = (unsigned short*)alloc((size_t)NM * 384 * 2);
    unsigned short* o_n    = (unsigned short*)alloc((size_t)NM * 512 * 2);
    unsigned short* h2     = (unsigned short*)alloc((size_t)NM * 512 * 2);
    unsigned short* act    = (unsigned short*)nb0_;
    // attention region
    float* kvf = (float*)alloc((size_t)NM * 1024 * 4);
    float* qff = (float*)alloc((size_t)NM * 768 * 4);
    _Float16* qgh = (_Float16*)alloc((size_t)NB * H2N * NS_PAD * 64 * 2);
    _Float16* qgl = (_Float16*)alloc((size_t)NB * H2N * NS_PAD * 64 * 2);
    _Float16* kgh = (_Float16*)alloc((size_t)NB * H2N * NS_PAD * 64 * 2);
    _Float16* kgl = (_Float16*)alloc((size_t)NB * H2N * NS_PAD * 64 * 2);
    _Float16* vt  = (_Float16*)alloc((size_t)NB * NH * 64 * NS_PAD * 2);
    float* P4     = (float*)alloc((size_t)NB * NH * SEQN * 64 * 4);
    float* Opart  = (float*)alloc((size_t)2 * 16 * NS * 128 * 4);
    float* zpart  = (float*)alloc((size_t)2 * 16 * NS * 4 * 4);

    // fused weight transposes (Wkvd/Wqd share wcq output; Wffi interleaved for swiglu)
    int cum = 0;
    {
        TD7 a;
        const float* ws_[7] = {Wkvd, Wqd, Wkvu, Wqu, Wo, Wffi, Wffo};
        unsigned short* his[7] = {wcq_h, wcq_h + (size_t)288 * 512, wkvu_h, wqu_h, wo_h, wffi_h, wffo_h};
        unsigned short* los[7] = {wcq_l, wcq_l + (size_t)288 * 512, wkvu_l, wqu_l, nullptr, nullptr, nullptr};
        int Ks[7] = {512, 512, 256, 384, 512, 512, 1536};
        int Ns[7] = {288, 384, 1024, 768, 512, 3072, 512};
        int pm[7] = {0, 0, 0, 0, 0, 1, 0};
        for (int i = 0; i < 7; i++) {
            a.d[i] = TD{ws_[i], his[i], los[i], Ks[i], Ns[i], pm[i]};
            cum += ((Ks[i] + 31) / 32) * ((Ns[i] + 31) / 32);
            a.tend[i] = cum;
        }
        transpose_all<<<dim3(cum), 256, 0, stream>>>(a);
    }

    rmsnorm_k<<<NM, 256, 0, stream>>>(x, n1w, h_hi, h_lo, 512, 512, EPS1);

    const int GX = (NM + 127) / 128;
    gemm_x3<<<dim3(GX, (672 + 63) / 64), 256, 0, stream>>>(h_hi, h_lo, wcq_h, wcq_l, cq, NM, 672, 512);

    rmsnorm_dual<<<NM, 256, 0, stream>>>(cq, kvnw, qnw, ckvn_h, ckvn_l, qdn_h, qdn_l);

    gemm_x3<<<dim3(GX, 1024 / 64), 256, 0, stream>>>(ckvn_h, ckvn_l, wkvu_h, wkvu_l, kvf, NM, 1024, 256);
    gemm_x3<<<dim3(GX, 768 / 64), 256, 0, stream>>>(qdn_h, qdn_l, wqu_h, wqu_l, qff, NM, 768, 384);

    {
        size_t total = (size_t)NB * H2N * NS_PAD * 32;
        assemble2<<<dim3((unsigned)((total + 255) / 256)), 256, 0, stream>>>(
            qff, kvf, cq, freqs, qgh, qgl, kgh, kgl);
    }
    vtrans<<<dim3(NS_PAD / 64, NB * NH), 256, 0, stream>>>(kvf, vt);
    prefix2_k<<<dim3(NB * NH), 256, 0, stream>>>(kvf, P4);

    flash_split<<<dim3((NS + 63) / 64, 16, NB), 256, 0, stream>>>(
        qgh, qgl, kgh, kgl, vt, Opart, zpart);
    combine_attn<<<dim3((NS + 63) / 64, NH, NB), 256, 0, stream>>>(
        Opart, zpart, kvf, P4, lq1, lk1, lq2, lk2, hnw, o_n);

    gemm_single<<<dim3(GX, 512 / 64), 256, 0, stream>>>(o_n, wo_h, x2, x, NM, 512, 512);
    rmsnorm_k<<<NM, 256, 0, stream>>>(x2, n2w, h2, nullptr, 512, 512, EPS1);
    gemm_swiglu<<<dim3(GX, 3072 / 64), 256, 0, stream>>>(h2, wffi_h, act, NM, 3072, 512);
    gemm_single<<<dim3(GX, 512 / 64), 256, 0, stream>>>(act, wffo_h, out, x2, NM, 512, 1536);
}

// Round 12
// 276.212 us; speedup vs baseline: 1.7813x; 1.4194x over previous
//
#include <hip/hip_runtime.h>

#define NB 2
#define SEQN 384
#define NS 1537
#define NS_PAD 1600
#define NH 8
#define H2N 16
#define NM (NB*NS)
#define DFF 1536
#define EPS1 1.1920929e-07f
#define SCAL (1.0f/48.0f)
#define SC2 (SCAL * 1.4426950408889634f)   // SCAL * log2(e), for exp2

// swizzled index into a [rows][64] 16-bit tile (16B-granule XOR swizzle)
#define SWZ(row, col) ((((row) << 6)) + ((col) ^ (((row) & 7) << 3)))

typedef __bf16 bf16x8 __attribute__((ext_vector_type(8)));
typedef _Float16 f16x8 __attribute__((ext_vector_type(8)));
typedef float f32x4 __attribute__((ext_vector_type(4)));

__device__ __forceinline__ unsigned short f2bf(float f) {
    unsigned int u = __builtin_bit_cast(unsigned int, f);
    u += 0x7FFFu + ((u >> 16) & 1u);
    return (unsigned short)(u >> 16);
}
__device__ __forceinline__ float bf2f(unsigned short h) {
    unsigned int u = ((unsigned int)h) << 16;
    return __builtin_bit_cast(float, u);
}

// ---------------- fused weight transpose (KxN f32 -> NxK bf16 hi[/lo]) ----------------
struct TD { const float* w; unsigned short* hi; unsigned short* lo; int K; int N; int perm; };
struct TD7 { TD d[7]; int tend[7]; };

__global__ __launch_bounds__(256) void transpose_all(TD7 a) {
    __shared__ float tile[32][33];
    int t = blockIdx.x;
    int i = 0;
    while (t >= a.tend[i]) i++;
    int base = (i == 0) ? 0 : a.tend[i - 1];
    int lt = t - base;
    const float* w = a.d[i].w;
    unsigned short* hi = a.d[i].hi;
    unsigned short* lo = a.d[i].lo;
    int K = a.d[i].K, N = a.d[i].N, perm = a.d[i].perm;
    int Nh = N >> 1;
    int kt = (K + 31) / 32;
    int k0 = (lt % kt) * 32, n0 = (lt / kt) * 32;
    int tx = threadIdx.x & 31, ty4 = (threadIdx.x >> 5) * 4;
    for (int q = 0; q < 4; q++) {
        int k = k0 + ty4 + q, n = n0 + tx;
        tile[ty4 + q][tx] = (k < K && n < N) ? w[(size_t)k * N + n] : 0.f;
    }
    __syncthreads();
    for (int q = 0; q < 4; q++) {
        int n = n0 + ty4 + q, k = k0 + tx;
        if (n < N && k < K) {
            float v = tile[tx][ty4 + q];
            unsigned short hb = f2bf(v);
            int n_out = perm ? ((n < Nh) ? 2 * n : 2 * (n - Nh) + 1) : n;
            size_t o = (size_t)n_out * K + k;
            hi[o] = hb;
            if (lo) lo[o] = f2bf(v - bf2f(hb));
        }
    }
}

// ---------------- rmsnorm (f32 in, bf16 hi[/lo] out) ----------------
__global__ __launch_bounds__(256) void rmsnorm_k(const float* __restrict__ in,
    const float* __restrict__ w, unsigned short* __restrict__ hi, unsigned short* __restrict__ lo,
    int in_stride, int C, float eps) {
    int row = blockIdx.x;
    const float* x = in + (size_t)row * in_stride;
    float ss = 0.f;
    for (int j = threadIdx.x; j < C; j += 256) { float v = x[j]; ss += v * v; }
    for (int o = 1; o < 64; o <<= 1) ss += __shfl_xor(ss, o);
    __shared__ float red[4];
    if ((threadIdx.x & 63) == 0) red[threadIdx.x >> 6] = ss;
    __syncthreads();
    ss = red[0] + red[1] + red[2] + red[3];
    float rs = rsqrtf(ss / (float)C + eps);
    for (int j = threadIdx.x; j < C; j += 256) {
        float y = x[j] * rs * w[j];
        unsigned short hb = f2bf(y);
        hi[(size_t)row * C + j] = hb;
        if (lo) lo[(size_t)row * C + j] = f2bf(y - bf2f(hb));
    }
}

// ---------------- dual rmsnorm: cq row -> ckvn (C=256) + qdn (C=384, cols 288..671) --
__global__ __launch_bounds__(256) void rmsnorm_dual(const float* __restrict__ cq,
    const float* __restrict__ wA, const float* __restrict__ wB,
    unsigned short* __restrict__ ah, unsigned short* __restrict__ al,
    unsigned short* __restrict__ bh_, unsigned short* __restrict__ bl_) {
    int row = blockIdx.x, tid = threadIdx.x;
    const float* xx = cq + (size_t)row * 672;
    __shared__ float red[4];
    float v = xx[tid & 255];
    float ss = v * v;
    for (int o = 1; o < 64; o <<= 1) ss += __shfl_xor(ss, o);
    if ((tid & 63) == 0) red[tid >> 6] = ss;
    __syncthreads();
    float tot = red[0] + red[1] + red[2] + red[3];
    float rs = rsqrtf(tot / 256.f + EPS1);
    float y = v * rs * wA[tid];
    unsigned short hb = f2bf(y);
    ah[(size_t)row * 256 + tid] = hb;
    al[(size_t)row * 256 + tid] = f2bf(y - bf2f(hb));
    __syncthreads();
    float v0 = xx[288 + tid];
    float v1 = (tid < 128) ? xx[288 + 256 + tid] : 0.f;
    float ss2 = v0 * v0 + v1 * v1;
    for (int o = 1; o < 64; o <<= 1) ss2 += __shfl_xor(ss2, o);
    if ((tid & 63) == 0) red[tid >> 6] = ss2;
    __syncthreads();
    tot = red[0] + red[1] + red[2] + red[3];
    rs = rsqrtf(tot / 384.f + EPS1);
    float yb = v0 * rs * wB[tid];
    hb = f2bf(yb);
    bh_[(size_t)row * 384 + tid] = hb;
    bl_[(size_t)row * 384 + tid] = f2bf(yb - bf2f(hb));
    if (tid < 128) {
        float yc = v1 * rs * wB[256 + tid];
        unsigned short hc = f2bf(yc);
        bh_[(size_t)row * 384 + 256 + tid] = hc;
        bl_[(size_t)row * 384 + 256 + tid] = f2bf(yc - bf2f(hc));
    }
}

// ------- single-bf16 GEMM, 128x64 tile, BK=64, swizzled LDS -------
__global__ __launch_bounds__(256) void gemm_single(const unsigned short* __restrict__ A,
    const unsigned short* __restrict__ Bt, float* __restrict__ C_, const float* __restrict__ res,
    int M, int N, int K) {
    __shared__ unsigned short As[128 * 64];
    __shared__ unsigned short Bs[64 * 64];
    int m0 = blockIdx.x * 128, n0 = blockIdx.y * 64;
    int tid = threadIdx.x;
    int lane = tid & 63, wid = tid >> 6;
    int wr = wid >> 1, wc = wid & 1;
    int r = lane & 15, g = lane >> 4;
    int lrow = tid >> 3, lk = (tid & 7) * 8;
    f32x4 acc[4][2] = {};
    bool aok[4]; size_t aoff[4];
    #pragma unroll
    for (int p = 0; p < 4; p++) {
        int ar = m0 + p * 32 + lrow;
        aok[p] = ar < M;
        aoff[p] = (size_t)ar * K + lk;
    }
    bool bok[2]; size_t boff[2];
    #pragma unroll
    for (int p = 0; p < 2; p++) {
        int br = n0 + p * 32 + lrow;
        bok[p] = br < N;
        boff[p] = (size_t)br * K + lk;
    }
    for (int k0 = 0; k0 < K; k0 += 64) {
        uint4 av[4], bv[2];
        #pragma unroll
        for (int p = 0; p < 4; p++) av[p] = aok[p] ? *(const uint4*)(A + aoff[p] + k0) : (uint4){0,0,0,0};
        #pragma unroll
        for (int p = 0; p < 2; p++) bv[p] = bok[p] ? *(const uint4*)(Bt + boff[p] + k0) : (uint4){0,0,0,0};
        __syncthreads();
        #pragma unroll
        for (int p = 0; p < 4; p++) *(uint4*)&As[SWZ(p * 32 + lrow, lk)] = av[p];
        #pragma unroll
        for (int p = 0; p < 2; p++) *(uint4*)&Bs[SWZ(p * 32 + lrow, lk)] = bv[p];
        __syncthreads();
        #pragma unroll
        for (int ks = 0; ks < 2; ks++) {
            bf16x8 a[4], bb[2];
            #pragma unroll
            for (int i = 0; i < 4; i++) a[i] = *(const bf16x8*)&As[SWZ(wr * 64 + i * 16 + r, ks * 32 + g * 8)];
            #pragma unroll
            for (int j = 0; j < 2; j++) bb[j] = *(const bf16x8*)&Bs[SWZ(wc * 32 + j * 16 + r, ks * 32 + g * 8)];
            #pragma unroll
            for (int i = 0; i < 4; i++)
                #pragma unroll
                for (int j = 0; j < 2; j++)
                    acc[i][j] = __builtin_amdgcn_mfma_f32_16x16x32_bf16(a[i], bb[j], acc[i][j], 0, 0, 0);
        }
    }
    #pragma unroll
    for (int i = 0; i < 4; i++)
        #pragma unroll
        for (int j = 0; j < 2; j++) {
            int col = n0 + wc * 32 + j * 16 + r;
            if (col >= N) continue;
            #pragma unroll
            for (int e = 0; e < 4; e++) {
                int row = m0 + wr * 64 + i * 16 + g * 4 + e;
                if (row >= M) continue;
                float v = acc[i][j][e];
                if (res) v += res[(size_t)row * N + col];
                C_[(size_t)row * N + col] = v;
            }
        }
}

// ------- GEMM + fused swiglu epilogue (interleaved u/g cols), BK=64 swizzled -------
__global__ __launch_bounds__(256) void gemm_swiglu(const unsigned short* __restrict__ A,
    const unsigned short* __restrict__ Bt, unsigned short* __restrict__ act,
    int M, int N, int K) {
    __shared__ unsigned short As[128 * 64];
    __shared__ unsigned short Bs[64 * 64];
    int m0 = blockIdx.x * 128, n0 = blockIdx.y * 64;
    int tid = threadIdx.x;
    int lane = tid & 63, wid = tid >> 6;
    int wr = wid >> 1, wc = wid & 1;
    int r = lane & 15, g = lane >> 4;
    int lrow = tid >> 3, lk = (tid & 7) * 8;
    f32x4 acc[4][2] = {};
    bool aok[4]; size_t aoff[4];
    #pragma unroll
    for (int p = 0; p < 4; p++) {
        int ar = m0 + p * 32 + lrow;
        aok[p] = ar < M;
        aoff[p] = (size_t)ar * K + lk;
    }
    bool bok[2]; size_t boff[2];
    #pragma unroll
    for (int p = 0; p < 2; p++) {
        int br = n0 + p * 32 + lrow;
        bok[p] = br < N;
        boff[p] = (size_t)br * K + lk;
    }
    for (int k0 = 0; k0 < K; k0 += 64) {
        uint4 av[4], bv[2];
        #pragma unroll
        for (int p = 0; p < 4; p++) av[p] = aok[p] ? *(const uint4*)(A + aoff[p] + k0) : (uint4){0,0,0,0};
        #pragma unroll
        for (int p = 0; p < 2; p++) bv[p] = bok[p] ? *(const uint4*)(Bt + boff[p] + k0) : (uint4){0,0,0,0};
        __syncthreads();
        #pragma unroll
        for (int p = 0; p < 4; p++) *(uint4*)&As[SWZ(p * 32 + lrow, lk)] = av[p];
        #pragma unroll
        for (int p = 0; p < 2; p++) *(uint4*)&Bs[SWZ(p * 32 + lrow, lk)] = bv[p];
        __syncthreads();
        #pragma unroll
        for (int ks = 0; ks < 2; ks++) {
            bf16x8 a[4], bb[2];
            #pragma unroll
            for (int i = 0; i < 4; i++) a[i] = *(const bf16x8*)&As[SWZ(wr * 64 + i * 16 + r, ks * 32 + g * 8)];
            #pragma unroll
            for (int j = 0; j < 2; j++) bb[j] = *(const bf16x8*)&Bs[SWZ(wc * 32 + j * 16 + r, ks * 32 + g * 8)];
            #pragma unroll
            for (int i = 0; i < 4; i++)
                #pragma unroll
                for (int j = 0; j < 2; j++)
                    acc[i][j] = __builtin_amdgcn_mfma_f32_16x16x32_bf16(a[i], bb[j], acc[i][j], 0, 0, 0);
        }
    }
    int Nh = N >> 1;
    #pragma unroll
    for (int i = 0; i < 4; i++)
        #pragma unroll
        for (int j = 0; j < 2; j++) {
            int col = n0 + wc * 32 + j * 16 + r;
            #pragma unroll
            for (int e = 0; e < 4; e++) {
                int row = m0 + wr * 64 + i * 16 + g * 4 + e;
                float v = acc[i][j][e];
                float o = __shfl_xor(v, 1);
                if (((r & 1) == 0) && row < M && col < N) {
                    float u = v, gg = o;
                    float sg = gg / (1.f + __expf(-gg));
                    act[(size_t)row * Nh + (col >> 1)] = f2bf(u * sg);
                }
            }
        }
}

// ------- split-bf16 (hi+lo, 3xMFMA) GEMM, 128x64 tile, BK=64 swizzled -------
__global__ __launch_bounds__(256) void gemm_x3(const unsigned short* __restrict__ Ah,
    const unsigned short* __restrict__ Al, const unsigned short* __restrict__ Bh,
    const unsigned short* __restrict__ Bl, float* __restrict__ C_, int M, int N, int K) {
    __shared__ unsigned short AsH[128 * 64], AsL[128 * 64], BsH[64 * 64], BsL[64 * 64];
    int m0 = blockIdx.x * 128, n0 = blockIdx.y * 64;
    int tid = threadIdx.x;
    int lane = tid & 63, wid = tid >> 6;
    int wr = wid >> 1, wc = wid & 1;
    int r = lane & 15, g = lane >> 4;
    int lrow = tid >> 3, lk = (tid & 7) * 8;
    f32x4 acc[4][2] = {};
    bool aok[4]; size_t aoff[4];
    #pragma unroll
    for (int p = 0; p < 4; p++) {
        int ar = m0 + p * 32 + lrow;
        aok[p] = ar < M;
        aoff[p] = (size_t)ar * K + lk;
    }
    bool bok[2]; size_t boff[2];
    #pragma unroll
    for (int p = 0; p < 2; p++) {
        int br = n0 + p * 32 + lrow;
        bok[p] = br < N;
        boff[p] = (size_t)br * K + lk;
    }
    for (int k0 = 0; k0 < K; k0 += 64) {
        uint4 avh[4], avl[4], bvh[2], bvl[2];
        #pragma unroll
        for (int p = 0; p < 4; p++) {
            avh[p] = aok[p] ? *(const uint4*)(Ah + aoff[p] + k0) : (uint4){0,0,0,0};
            avl[p] = aok[p] ? *(const uint4*)(Al + aoff[p] + k0) : (uint4){0,0,0,0};
        }
        #pragma unroll
        for (int p = 0; p < 2; p++) {
            bvh[p] = bok[p] ? *(const uint4*)(Bh + boff[p] + k0) : (uint4){0,0,0,0};
            bvl[p] = bok[p] ? *(const uint4*)(Bl + boff[p] + k0) : (uint4){0,0,0,0};
        }
        __syncthreads();
        #pragma unroll
        for (int p = 0; p < 4; p++) {
            *(uint4*)&AsH[SWZ(p * 32 + lrow, lk)] = avh[p];
            *(uint4*)&AsL[SWZ(p * 32 + lrow, lk)] = avl[p];
        }
        #pragma unroll
        for (int p = 0; p < 2; p++) {
            *(uint4*)&BsH[SWZ(p * 32 + lrow, lk)] = bvh[p];
            *(uint4*)&BsL[SWZ(p * 32 + lrow, lk)] = bvl[p];
        }
        __syncthreads();
        #pragma unroll
        for (int ks = 0; ks < 2; ks++) {
            bf16x8 ah[4], al[4], bh[2], bl[2];
            #pragma unroll
            for (int i = 0; i < 4; i++) {
                int ai = SWZ(wr * 64 + i * 16 + r, ks * 32 + g * 8);
                ah[i] = *(const bf16x8*)&AsH[ai];
                al[i] = *(const bf16x8*)&AsL[ai];
            }
            #pragma unroll
            for (int j = 0; j < 2; j++) {
                int bi = SWZ(wc * 32 + j * 16 + r, ks * 32 + g * 8);
                bh[j] = *(const bf16x8*)&BsH[bi];
                bl[j] = *(const bf16x8*)&BsL[bi];
            }
            #pragma unroll
            for (int i = 0; i < 4; i++)
                #pragma unroll
                for (int j = 0; j < 2; j++) {
                    acc[i][j] = __builtin_amdgcn_mfma_f32_16x16x32_bf16(al[i], bh[j], acc[i][j], 0, 0, 0);
                    acc[i][j] = __builtin_amdgcn_mfma_f32_16x16x32_bf16(ah[i], bl[j], acc[i][j], 0, 0, 0);
                    acc[i][j] = __builtin_amdgcn_mfma_f32_16x16x32_bf16(ah[i], bh[j], acc[i][j], 0, 0, 0);
                }
        }
    }
    #pragma unroll
    for (int i = 0; i < 4; i++)
        #pragma unroll
        for (int j = 0; j < 2; j++) {
            int col = n0 + wc * 32 + j * 16 + r;
            if (col >= N) continue;
            #pragma unroll
            for (int e = 0; e < 4; e++) {
                int row = m0 + wr * 64 + i * 16 + g * 4 + e;
                if (row < M) C_[(size_t)row * N + col] = acc[i][j][e];
            }
        }
}

// ---------------- assemble q/k heads (f16 hi/lo, RoPE applied, padded 48->64) ------
__global__ void assemble2(const float* __restrict__ qf_, const float* __restrict__ kvf,
    const float* __restrict__ cq, const float* __restrict__ freqs,
    _Float16* __restrict__ qgh, _Float16* __restrict__ qgl,
    _Float16* __restrict__ kgh, _Float16* __restrict__ kgl) {
    size_t idx = (size_t)blockIdx.x * 256 + threadIdx.x;
    const size_t total = (size_t)NB * H2N * NS_PAD * 32;
    if (idx >= total) return;
    int j2 = (int)(idx & 31);
    size_t t = idx >> 5;
    int s = (int)(t % NS_PAD); size_t r = t / NS_PAD;
    int sub = (int)(r & 1); r >>= 1;
    int h = (int)(r & 7); int b = (int)(r >> 3);
    float2 qv = make_float2(0.f, 0.f), kv2 = make_float2(0.f, 0.f);
    if (s < NS && j2 < 24) {
        size_t bs = (size_t)b * NS + s;
        if (j2 < 16) {
            const float* qp = qf_ + bs * 768 + h * 96 + sub * 32 + j2 * 2;
            qv = make_float2(qp[0], qp[1]);
            const float* kp = kvf + bs * 1024 + h * 128 + sub * 32 + j2 * 2;
            kv2 = make_float2(kp[0], kp[1]);
        } else {
            int i = j2 - 16;
            const float* qp = qf_ + bs * 768 + h * 96 + 64 + sub * 16 + 2 * i;
            float xr = qp[0], xi = qp[1];
            const float* kp = cq + bs * 672 + 256 + sub * 16 + 2 * i;
            float yr = kp[0], yi = kp[1];
            if (s == 0) {
                qv = make_float2(xr, xi);
                kv2 = make_float2(yr, yi);
            } else {
                int pos = (s - 1) % SEQN;
                float c = freqs[pos * 16 + 2 * i], sn = freqs[pos * 16 + 2 * i + 1];
                qv = make_float2(xr * c - xi * sn, xr * sn + xi * c);
                kv2 = make_float2(yr * c - yi * sn, yr * sn + yi * c);
            }
        }
    }
    _Float16 qx = (_Float16)qv.x, qy = (_Float16)qv.y;
    _Float16 kx = (_Float16)kv2.x, ky = (_Float16)kv2.y;
    qgh[idx * 2] = qx; qgh[idx * 2 + 1] = qy;
    kgh[idx * 2] = kx; kgh[idx * 2 + 1] = ky;
    qgl[idx * 2] = (_Float16)(qv.x - (float)qx); qgl[idx * 2 + 1] = (_Float16)(qv.y - (float)qy);
    kgl[idx * 2] = (_Float16)(kv2.x - (float)kx); kgl[idx * 2 + 1] = (_Float16)(kv2.y - (float)ky);
}

// ---------------- V transpose: kvf -> vt [ (b*8+h)*64 + d ][ NS_PAD ] f16 ----------------
__global__ __launch_bounds__(256) void vtrans(const float* __restrict__ kvf,
                                              _Float16* __restrict__ vt) {
    __shared__ float tile[64][65];
    int k0 = blockIdx.x * 64;
    int b = blockIdx.y >> 3, h = blockIdx.y & 7;
    int tid = threadIdx.x;
    int row = tid >> 2, cq_ = (tid & 3) * 16;
    for (int i = 0; i < 16; i++) {
        int key = k0 + row;
        tile[row][cq_ + i] = (key < NS)
            ? kvf[((size_t)(b * NS + key)) * 1024 + h * 128 + 64 + cq_ + i] : 0.f;
    }
    __syncthreads();
    int d = tid >> 2, kq = (tid & 3) * 16;
    for (int i = 0; i < 16; i++)
        vt[((size_t)((b * 8 + h) * 64 + d)) * NS_PAD + k0 + kq + i] = (_Float16)tile[kq + i][d];
}

// ------- fused chunk-sum + prefix, 1024 threads: 16 chunks of 24 positions ----------
__global__ __launch_bounds__(1024) void prefix2_k(const float* __restrict__ kvf,
                                                  float* __restrict__ P4) {
    __shared__ float tot[16][64];
    int bh = blockIdx.x; int b = bh >> 3, h = bh & 7;
    int d = threadIdx.x & 63, ps = threadIdx.x >> 6;   // ps in 0..15
    int p0 = ps * 24;
    float run = 0.f;
    for (int i = 0; i < 24; i++) {
        int p = p0 + i;
        float s = 0.f;
        #pragma unroll
        for (int c = 0; c < 4; c++)
            s += kvf[((size_t)(b * NS + 1 + c * SEQN + p)) * 1024 + h * 128 + 64 + d];
        run += s;
        P4[((size_t)bh * SEQN + p) * 64 + d] = run;
    }
    tot[ps][d] = run;
    __syncthreads();
    if (ps > 0) {
        float off = 0.f;
        for (int j = 0; j < ps; j++) off += tot[j][d];
        for (int i = 0; i < 24; i++)
            P4[((size_t)bh * SEQN + p0 + i) * 64 + d] += off;
    }
}

// ------- flash differential attention, contiguous chunk-pair split, swizzled 48KB LDS ----
// (R9 configuration: best measured — LDS-staged, setprio around MFMA clusters)
__global__ __launch_bounds__(256) void flash_split(
    const _Float16* __restrict__ qgh, const _Float16* __restrict__ qgl,
    const _Float16* __restrict__ kgh, const _Float16* __restrict__ kgl,
    const _Float16* __restrict__ vt,
    float* __restrict__ Opart, float* __restrict__ zpart) {
    __shared__ _Float16 Ksh[2][64 * 64];
    __shared__ _Float16 Ksl[2][64 * 64];
    __shared__ _Float16 Vt[64 * 64];
    __shared__ _Float16 Pl[4][16 * 64];
    const int tile = blockIdx.x;
    const int h = blockIdx.y & 7, split = blockIdx.y >> 3;
    const int b = blockIdx.z;
    const int bh = b * 8 + h;
    const int qs0 = tile * 64;
    const int tid = threadIdx.x;
    const int wave = tid >> 6, lane = tid & 63;
    const int r = lane & 15, g = lane >> 4;
    const int qrow = qs0 + wave * 16;
    const size_t sh0 = (size_t)(bh * 2);

    f16x8 qfh[2][2], qfl[2][2];
    #pragma unroll
    for (int sub = 0; sub < 2; sub++)
        #pragma unroll
        for (int ks = 0; ks < 2; ks++) {
            size_t off = ((sh0 + sub) * NS_PAD + qrow + r) * 64 + ks * 32 + g * 8;
            qfh[sub][ks] = *(const f16x8*)(qgh + off);
            qfl[sub][ks] = *(const f16x8*)(qgl + off);
        }

    float z0p[4] = {0.f,0.f,0.f,0.f}, g0p[4] = {0.f,0.f,0.f,0.f}, z1p[4] = {0.f,0.f,0.f,0.f};
    f32x4 O0[4], O1[4];
    #pragma unroll
    for (int e = 0; e < 4; e++) { O0[e] = (f32x4){0.f,0.f,0.f,0.f}; O1[e] = (f32x4){0.f,0.f,0.f,0.f}; }
    int qpos[4];
    #pragma unroll
    for (int e = 0; e < 4; e++) {
        int q = qrow + g * 4 + e;
        qpos[e] = (q == 0) ? -1 : (q - 1) % SEQN;
    }
    int lo = qs0 < 1 ? 1 : qs0;
    int hi = qs0 + 63 < NS - 1 ? qs0 + 63 : NS - 1;
    int maxpos = ((lo - 1) / SEQN != (hi - 1) / SEQN) ? (SEQN - 1) : (hi - 1) % SEQN;

    for (int c = 2 * split; c < 2 * split + 2; c++) {
        int nb = (c == 0) ? ((maxpos + 2 + 63) >> 6) : ((maxpos + 1 + 63) >> 6);
        int kstart = (c == 0) ? 0 : (c * SEQN + 1);
        int cbase = c * SEQN + 1;
        for (int j = 0; j < nb; j++) {
            int kbase = kstart + j * 64;
            __syncthreads();
            #pragma unroll
            for (int i = 0; i < 4; i++) {
                int chunk = i * 256 + tid;
                int arr = chunk >> 9;
                int cc = chunk & 511;
                int row = cc >> 3, c8 = (cc & 7) * 8;
                size_t goff = ((sh0 + arr) * NS_PAD + kbase + row) * 64 + c8;
                int di = SWZ(row, c8);
                *(uint4*)&Ksh[arr][di] = *(const uint4*)(kgh + goff);
                *(uint4*)&Ksl[arr][di] = *(const uint4*)(kgl + goff);
            }
            #pragma unroll
            for (int i = 0; i < 2; i++) {
                int cc = i * 256 + tid;
                int d = cc >> 3, c8 = (cc & 7) * 8;
                *(uint4*)&Vt[SWZ(d, c8)] =
                    *(const uint4*)(vt + ((size_t)(bh * 64 + d)) * NS_PAD + kbase + c8);
            }
            __syncthreads();

            f16x8 bv[4][2];
            #pragma unroll
            for (int dt = 0; dt < 4; dt++)
                #pragma unroll
                for (int ks = 0; ks < 2; ks++)
                    bv[dt][ks] = *(const f16x8*)&Vt[SWZ(dt * 16 + r, ks * 32 + g * 8)];

            bool um[4][4];
            #pragma unroll
            for (int t4 = 0; t4 < 4; t4++) {
                int kk2 = kbase + t4 * 16 + r;
                int rel = kk2 - cbase;
                #pragma unroll
                for (int e = 0; e < 4; e++)
                    um[e][t4] = (kk2 == 0) ||
                                ((unsigned)rel < (unsigned)SEQN && rel <= qpos[e]);
            }

            #pragma unroll
            for (int sub = 0; sub < 2; sub++) {
                f32x4 acc[4];
                #pragma unroll
                for (int t4 = 0; t4 < 4; t4++) acc[t4] = (f32x4){0.f,0.f,0.f,0.f};
                __builtin_amdgcn_s_setprio(1);
                #pragma unroll
                for (int t4 = 0; t4 < 4; t4++)
                    #pragma unroll
                    for (int ks = 0; ks < 2; ks++) {
                        int ki = SWZ(t4 * 16 + r, ks * 32 + g * 8);
                        f16x8 bkh = *(const f16x8*)&Ksh[sub][ki];
                        f16x8 bkl = *(const f16x8*)&Ksl[sub][ki];
                        acc[t4] = __builtin_amdgcn_mfma_f32_16x16x32_f16(qfl[sub][ks], bkh, acc[t4], 0, 0, 0);
                        acc[t4] = __builtin_amdgcn_mfma_f32_16x16x32_f16(qfh[sub][ks], bkl, acc[t4], 0, 0, 0);
                        acc[t4] = __builtin_amdgcn_mfma_f32_16x16x32_f16(qfh[sub][ks], bkh, acc[t4], 0, 0, 0);
                    }
                __builtin_amdgcn_s_setprio(0);
                #pragma unroll
                for (int e = 0; e < 4; e++) {
                    #pragma unroll
                    for (int t4 = 0; t4 < 4; t4++) {
                        float a = acc[t4][e];
                        float ef = exp2f(fabsf(a) * SC2);
                        float ev = um[e][t4] ? ef : 0.f;
                        float pvv = copysignf(ev, a);
                        if (sub == 0) { z0p[e] += ev; g0p[e] += pvv; }
                        else          { z1p[e] += ev; }
                        Pl[wave][SWZ(g * 4 + e, t4 * 16 + r)] = (_Float16)pvv;
                    }
                }
                __builtin_amdgcn_wave_barrier();
                f16x8 pa0 = *(const f16x8*)&Pl[wave][SWZ(r, g * 8)];
                f16x8 pa1 = *(const f16x8*)&Pl[wave][SWZ(r, 32 + g * 8)];
                __builtin_amdgcn_s_setprio(1);
                #pragma unroll
                for (int dt = 0; dt < 4; dt++) {
                    if (sub == 0) {
                        O0[dt] = __builtin_amdgcn_mfma_f32_16x16x32_f16(pa0, bv[dt][0], O0[dt], 0, 0, 0);
                        O0[dt] = __builtin_amdgcn_mfma_f32_16x16x32_f16(pa1, bv[dt][1], O0[dt], 0, 0, 0);
                    } else {
                        O1[dt] = __builtin_amdgcn_mfma_f32_16x16x32_f16(pa0, bv[dt][0], O1[dt], 0, 0, 0);
                        O1[dt] = __builtin_amdgcn_mfma_f32_16x16x32_f16(pa1, bv[dt][1], O1[dt], 0, 0, 0);
                    }
                }
                __builtin_amdgcn_s_setprio(0);
            }
        }
    }

    // write partials to this split's slot
    #pragma unroll
    for (int e = 0; e < 4; e++) {
        float z0 = z0p[e], g0 = g0p[e], z1 = z1p[e];
        #pragma unroll
        for (int o = 1; o < 16; o <<= 1) {
            z0 += __shfl_xor(z0, o); g0 += __shfl_xor(g0, o); z1 += __shfl_xor(z1, o);
        }
        int q = qrow + g * 4 + e;
        if (q < NS) {
            if (r == 0) {
                float* zp = zpart + (((size_t)split * 16 + bh) * NS + q) * 4;
                zp[0] = z0; zp[1] = g0; zp[2] = z1;
            }
            float* op = Opart + (((size_t)split * 16 + bh) * NS + q) * 128;
            #pragma unroll
            for (int dt = 0; dt < 4; dt++) {
                op[dt * 16 + r] = O0[dt][e];
                op[64 + dt * 16 + r] = O1[dt][e];
            }
        }
    }
}

// ------- combine partials: lambda (inline) + G-term + head rmsnorm -> o_n (bf16) -------
__global__ __launch_bounds__(256) void combine_attn(const float* __restrict__ Opart,
    const float* __restrict__ zpart, const float* __restrict__ kvf,
    const float* __restrict__ P4,
    const float* __restrict__ lq1, const float* __restrict__ lk1,
    const float* __restrict__ lq2, const float* __restrict__ lk2,
    const float* __restrict__ hw, unsigned short* __restrict__ o_n) {
    __shared__ float lamS;
    if (threadIdx.x < 32) {
        float p1 = lq1[threadIdx.x] * lk1[threadIdx.x];
        float p2 = lq2[threadIdx.x] * lk2[threadIdx.x];
        for (int o = 1; o < 32; o <<= 1) { p1 += __shfl_xor(p1, o); p2 += __shfl_xor(p2, o); }
        if (threadIdx.x == 0) lamS = expf(p1) - expf(p2) + 0.2f;
    }
    __syncthreads();
    float lam = lamS;
    int b = blockIdx.z, h = blockIdx.y, bh = b * 8 + h;
    int ql = threadIdx.x >> 2, dp = threadIdx.x & 3;
    int q = blockIdx.x * 64 + ql;
    bool ok = q < NS;
    int qc = ok ? q : 0;
    size_t i0 = ((size_t)0 * 16 + bh) * NS + qc;
    size_t i1 = ((size_t)1 * 16 + bh) * NS + qc;
    const float* za = zpart + i0 * 4;
    const float* zb = zpart + i1 * 4;
    float z0 = za[0] + zb[0], g0 = za[1] + zb[1], z1 = za[2] + zb[2];
    float iz0 = 1.f / z0;
    float l1 = lam / z1;
    float Gl = lam * g0 * iz0 * (1.f / (float)NS);
    int qpos = (q == 0) ? -1 : (q - 1) % SEQN;
    const float* oa = Opart + i0 * 128 + dp * 16;
    const float* ob = Opart + i1 * 128 + dp * 16;
    float of[16]; float ss = 0.f;
    #pragma unroll
    for (int i = 0; i < 16; i++) {
        int d = dp * 16 + i;
        float O0 = oa[i] + ob[i];
        float O1 = oa[64 + i] + ob[64 + i];
        float vs = kvf[((size_t)(b * NS)) * 1024 + h * 128 + 64 + d];
        if (qpos >= 0) vs += P4[((size_t)bh * SEQN + qpos) * 64 + d];
        float o = O0 * iz0 - O1 * l1 + Gl * vs;
        of[i] = o; ss += o * o;
    }
    ss += __shfl_xor(ss, 1); ss += __shfl_xor(ss, 2);
    float rs = rsqrtf(ss / 64.f + 1e-5f);
    if (ok) {
        unsigned int pk[8];
        #pragma unroll
        for (int i = 0; i < 8; i++) {
            unsigned int a = f2bf(of[2 * i] * rs * hw[dp * 16 + 2 * i]);
            unsigned int c = f2bf(of[2 * i + 1] * rs * hw[dp * 16 + 2 * i + 1]);
            pk[i] = a | (c << 16);
        }
        unsigned short* dst = o_n + ((size_t)(b * NS + q)) * 512 + h * 64 + dp * 16;
        *(uint4*)dst = *(uint4*)&pk[0];
        *(uint4*)(dst + 8) = *(uint4*)&pk[4];
    }
}

// ---------------- host ----------------
extern "C" void kernel_launch(void* const* d_in, const int* in_sizes, int n_in,
                              void* d_out, int out_size, void* d_ws, size_t ws_size,
                              hipStream_t stream) {
    (void)in_sizes; (void)n_in; (void)out_size; (void)ws_size;
    const float* x    = (const float*)d_in[0];
    const float* freqs= (const float*)d_in[1];
    const float* Wkvd = (const float*)d_in[2];
    const float* Wqd  = (const float*)d_in[3];
    const float* Wkvu = (const float*)d_in[4];
    const float* Wqu  = (const float*)d_in[5];
    const float* kvnw = (const float*)d_in[6];
    const float* qnw  = (const float*)d_in[7];
    const float* Wo   = (const float*)d_in[8];
    const float* lq1  = (const float*)d_in[9];
    const float* lk1  = (const float*)d_in[10];
    const float* lq2  = (const float*)d_in[11];
    const float* lk2  = (const float*)d_in[12];
    const float* hnw  = (const float*)d_in[13];
    const float* n1w  = (const float*)d_in[14];
    const float* n2w  = (const float*)d_in[15];
    const float* Wffi = (const float*)d_in[16];
    const float* Wffo = (const float*)d_in[17];
    float* out = (float*)d_out;

    char* p = (char*)d_ws;
    auto alloc = [&](size_t nbytes) -> char* {
        char* r = p; p += (nbytes + 255) & ~(size_t)255; return r;
    };
    // weights (wcq = combined Wkvd|Wqd, N=672)
    unsigned short* wcq_h  = (unsigned short*)alloc((size_t)672 * 512 * 2);
    unsigned short* wcq_l  = (unsigned short*)alloc((size_t)672 * 512 * 2);
    unsigned short* wkvu_h = (unsigned short*)alloc((size_t)256 * 1024 * 2);
    unsigned short* wkvu_l = (unsigned short*)alloc((size_t)256 * 1024 * 2);
    unsigned short* wqu_h  = (unsigned short*)alloc((size_t)384 * 768 * 2);
    unsigned short* wqu_l  = (unsigned short*)alloc((size_t)384 * 768 * 2);
    unsigned short* wo_h   = (unsigned short*)alloc((size_t)512 * 512 * 2);
    unsigned short* wffi_h = (unsigned short*)alloc((size_t)512 * 3072 * 2);
    unsigned short* wffo_h = (unsigned short*)alloc((size_t)1536 * 512 * 2);
    unsigned short* h_hi   = (unsigned short*)alloc((size_t)NM * 512 * 2);
    unsigned short* h_lo   = (unsigned short*)alloc((size_t)NM * 512 * 2);
    // cq (3074 x 672) — aliased later by x2
    char* cq0 = p;
    float* cq = (float*)alloc((size_t)NM * 672 * 4);
    float* x2 = (float*)cq0;
    // norm block — act aliases the front
    char* nb0_ = p;
    unsigned short* ckvn_h = (unsigned short*)alloc((size_t)NM * 256 * 2);
    unsigned short* ckvn_l = (unsigned short*)alloc((size_t)NM * 256 * 2);
    unsigned short* qdn_h  = (unsigned short*)alloc((size_t)NM * 384 * 2);
    unsigned short* qdn_l  = (unsigned short*)alloc((size_t)NM * 384 * 2);
    unsigned short* o_n    = (unsigned short*)alloc((size_t)NM * 512 * 2);
    unsigned short* h2     = (unsigned short*)alloc((size_t)NM * 512 * 2);
    unsigned short* act    = (unsigned short*)nb0_;
    // attention region
    float* kvf = (float*)alloc((size_t)NM * 1024 * 4);
    float* qff = (float*)alloc((size_t)NM * 768 * 4);
    _Float16* qgh = (_Float16*)alloc((size_t)NB * H2N * NS_PAD * 64 * 2);
    _Float16* qgl = (_Float16*)alloc((size_t)NB * H2N * NS_PAD * 64 * 2);
    _Float16* kgh = (_Float16*)alloc((size_t)NB * H2N * NS_PAD * 64 * 2);
    _Float16* kgl = (_Float16*)alloc((size_t)NB * H2N * NS_PAD * 64 * 2);
    _Float16* vt  = (_Float16*)alloc((size_t)NB * NH * 64 * NS_PAD * 2);
    float* P4     = (float*)alloc((size_t)NB * NH * SEQN * 64 * 4);
    float* Opart  = (float*)alloc((size_t)2 * 16 * NS * 128 * 4);
    float* zpart  = (float*)alloc((size_t)2 * 16 * NS * 4 * 4);

    // fused weight transposes (Wkvd/Wqd share wcq output; Wffi interleaved for swiglu)
    int cum = 0;
    {
        TD7 a;
        const float* ws_[7] = {Wkvd, Wqd, Wkvu, Wqu, Wo, Wffi, Wffo};
        unsigned short* his[7] = {wcq_h, wcq_h + (size_t)288 * 512, wkvu_h, wqu_h, wo_h, wffi_h, wffo_h};
        unsigned short* los[7] = {wcq_l, wcq_l + (size_t)288 * 512, wkvu_l, wqu_l, nullptr, nullptr, nullptr};
        int Ks[7] = {512, 512, 256, 384, 512, 512, 1536};
        int Ns[7] = {288, 384, 1024, 768, 512, 3072, 512};
        int pm[7] = {0, 0, 0, 0, 0, 1, 0};
        for (int i = 0; i < 7; i++) {
            a.d[i] = TD{ws_[i], his[i], los[i], Ks[i], Ns[i], pm[i]};
            cum += ((Ks[i] + 31) / 32) * ((Ns[i] + 31) / 32);
            a.tend[i] = cum;
        }
        transpose_all<<<dim3(cum), 256, 0, stream>>>(a);
    }

    rmsnorm_k<<<NM, 256, 0, stream>>>(x, n1w, h_hi, h_lo, 512, 512, EPS1);

    const int GX = (NM + 127) / 128;
    gemm_x3<<<dim3(GX, (672 + 63) / 64), 256, 0, stream>>>(h_hi, h_lo, wcq_h, wcq_l, cq, NM, 672, 512);

    rmsnorm_dual<<<NM, 256, 0, stream>>>(cq, kvnw, qnw, ckvn_h, ckvn_l, qdn_h, qdn_l);

    gemm_x3<<<dim3(GX, 1024 / 64), 256, 0, stream>>>(ckvn_h, ckvn_l, wkvu_h, wkvu_l, kvf, NM, 1024, 256);
    gemm_x3<<<dim3(GX, 768 / 64), 256, 0, stream>>>(qdn_h, qdn_l, wqu_h, wqu_l, qff, NM, 768, 384);

    {
        size_t total = (size_t)NB * H2N * NS_PAD * 32;
        assemble2<<<dim3((unsigned)((total + 255) / 256)), 256, 0, stream>>>(
            qff, kvf, cq, freqs, qgh, qgl, kgh, kgl);
    }
    vtrans<<<dim3(NS_PAD / 64, NB * NH), 256, 0, stream>>>(kvf, vt);
    prefix2_k<<<dim3(NB * NH), 1024, 0, stream>>>(kvf, P4);

    flash_split<<<dim3((NS + 63) / 64, 16, NB), 256, 0, stream>>>(
        qgh, qgl, kgh, kgl, vt, Opart, zpart);
    combine_attn<<<dim3((NS + 63) / 64, NH, NB), 256, 0, stream>>>(
        Opart, zpart, kvf, P4, lq1, lk1, lq2, lk2, hnw, o_n);

    gemm_single<<<dim3(GX, 512 / 64), 256, 0, stream>>>(o_n, wo_h, x2, x, NM, 512, 512);
    rmsnorm_k<<<NM, 256, 0, stream>>>(x2, n2w, h2, nullptr, 512, 512, EPS1);
    gemm_swiglu<<<dim3(GX, 3072 / 64), 256, 0, stream>>>(h2, wffi_h, act, NM, 3072, 512);
    gemm_single<<<dim3(GX, 512 / 64), 256, 0, stream>>>(act, wffo_h, out, x2, NM, 512, 1536);
}